// Round 14
// baseline (1450.812 us; speedup 1.0000x reference)
//
#include <hip/hip_runtime.h>
#include <stdint.h>
#include <math.h>

#define B_SZ 1024
#define NV   4096
#define NH   4096
#define NSGN 2048

typedef short bf16x8 __attribute__((ext_vector_type(8)));
typedef short bf16x4 __attribute__((ext_vector_type(4)));
typedef float f32x4  __attribute__((ext_vector_type(4)));
typedef _Float16 f16x8 __attribute__((ext_vector_type(8)));

#define F16_ONE  ((short)0x3C00)
#define F16_NEG1 ((short)0xBC00)

// ---------------- threefry2x32 (JAX-compatible, 20 rounds) ----------------
__host__ __device__ __forceinline__ void tf2x32(uint32_t k0, uint32_t k1,
                                                uint32_t x0, uint32_t x1,
                                                uint32_t& o0, uint32_t& o1)
{
    uint32_t k2 = k0 ^ k1 ^ 0x1BD11BDAu;
#define TFR(r) { x0 += x1; x1 = (x1 << (r)) | (x1 >> (32 - (r))); x1 ^= x0; }
    x0 += k0; x1 += k1;
    TFR(13) TFR(15) TFR(26) TFR(6)
    x0 += k1; x1 += k2 + 1u;
    TFR(17) TFR(29) TFR(16) TFR(24)
    x0 += k2; x1 += k0 + 2u;
    TFR(13) TFR(15) TFR(26) TFR(6)
    x0 += k0; x1 += k1 + 3u;
    TFR(17) TFR(29) TFR(16) TFR(24)
    x0 += k1; x1 += k2 + 4u;
    TFR(13) TFR(15) TFR(26) TFR(6)
    x0 += k2; x1 += k0 + 5u;
#undef TFR
    o0 = x0; o1 = x1;
}

__device__ __forceinline__ float tf_uniform01(uint32_t k0, uint32_t k1, uint32_t idx)
{
    uint32_t a, b;
    tf2x32(k0, k1, 0u, idx, a, b);
    uint32_t bits = a ^ b;
    uint32_t fb = (bits >> 9) | 0x3F800000u;
    return __uint_as_float(fb) - 1.0f;
}

__device__ __forceinline__ float sigmoidf_(float x)
{
    if (x >= 0.0f) { float e = expf(-x); return 1.0f / (1.0f + e); }
    float e = expf(x); return e / (1.0f + e);
}

__device__ __forceinline__ void gl16(const void* g, void* l)
{
    __builtin_amdgcn_global_load_lds((const __attribute__((address_space(1))) void*)g,
                                     (__attribute__((address_space(3))) void*)l, 16, 0, 0);
}

// ---------------- weight precompute: fp32 -> fp16 direct + transposed ----------------
__global__ __launch_bounds__(256) void conv_tr(const float* __restrict__ W,
                                               short* __restrict__ Wf,
                                               short* __restrict__ Wt)
{
    __shared__ short t[64][65];
    const int bx = blockIdx.x * 64;
    const int by = blockIdx.y * 64;
    const int r0 = threadIdx.x >> 4;
    const int c0 = (threadIdx.x & 15) * 4;
#pragma unroll
    for (int i = 0; i < 4; ++i) {
        int row = by + r0 + i * 16;
        f32x4 v = *(const f32x4*)(W + (size_t)row * 4096 + bx + c0);
        short h[4];
#pragma unroll
        for (int j = 0; j < 4; ++j) {
            union { _Float16 f; short s; } u;
            u.f = (_Float16)v[j];
            h[j] = u.s;
        }
        *(bf16x4*)(Wf + (size_t)row * 4096 + bx + c0) = *(bf16x4*)h;
#pragma unroll
        for (int j = 0; j < 4; ++j) t[c0 + j][r0 + i * 16] = h[j];
    }
    __syncthreads();
#pragma unroll
    for (int i = 0; i < 4; ++i) {
        int orow = r0 + i * 16;
        short o[4] = { t[orow][c0], t[orow][c0 + 1], t[orow][c0 + 2], t[orow][c0 + 3] };
        *(bf16x4*)(Wt + (size_t)(bx + orow) * 4096 + by + c0) = *(bf16x4*)o;
    }
}

// =====================================================================
// m97-replica chunk GEMM: 128x128 tile, BK=32, 256 thr = 4 waves (64x64
// each, 16 MFMA/step), 32 KB LDS dbuf, 4 gl16/wave/step, 64 steps =
// K-chunk 2048. Writes f32 partials P[ck][1024][NW].
// Slot order = 2pn x 4bm L2 supertiles (A+B working set ~4 MB = one L2),
// ck slowest. 4 blocks/CU.
//  MODE 0: K=4096 -> 2 chunks (A0,B0). grid 512.
//  MODE 1: K=8192 concat -> 4 chunks (A0,B0 then A1,B1). grid 1024.
//  MODE 2: dual-N 8192 (64 panels: B0=W2f pn<32, B1=W1T), K=4096 ->
//          2 chunks. grid 1024.
// =====================================================================
template<int MODE>
__global__ __launch_bounds__(256, 4) void mm_chunk(
    const short* __restrict__ A0, const short* __restrict__ A1,
    const short* __restrict__ B0, const short* __restrict__ B1,
    float* __restrict__ P)
{
    __shared__ __align__(1024) short As[2][8 * 512];
    __shared__ __align__(1024) short Bs[2][8 * 512];

    const int bid = blockIdx.x;
    const int xcd = bid & 7, slot = bid >> 3;

    // supertile decode: pn2 fastest, bm4, then pn-group, bm-group, ck slowest
    const int pn2 = slot & 1;
    const int bm4 = (slot >> 1) & 3;

    int bm, bncol, ck, kbase, NW;
    const short* Ap;
    const short* Bp;
    if (MODE == 2) {
        const int pnP = (slot >> 3) & 3;
        const int bmP = (slot >> 5) & 1;
        ck = (slot >> 6) & 1;
        int pn = xcd * 8 + pnP * 2 + pn2;       // 0..63
        bm = (bmP * 4 + bm4) * 128;
        kbase = ck * 2048;
        Ap = A0;
        Bp = (pn < 32) ? (B0 + (size_t)pn * 128 * 4096)
                       : (B1 + (size_t)(pn - 32) * 128 * 4096);
        bncol = pn * 128;
        NW = 8192;
    } else {
        const int pnP = (slot >> 3) & 1;
        const int bmP = (slot >> 4) & 1;
        ck = slot >> 5;                         // MODE0: 0..1, MODE1: 0..3
        int pn = xcd * 4 + pnP * 2 + pn2;       // 0..31
        bm = (bmP * 4 + bm4) * 128;
        if (MODE == 1 && ck >= 2) {
            Ap = A1; Bp = B1 + (size_t)pn * 128 * 4096; kbase = (ck - 2) * 2048;
        } else {
            Ap = A0; Bp = B0 + (size_t)pn * 128 * 4096; kbase = ck * 2048;
        }
        bncol = pn * 128;
        NW = 4096;
    }

    const int tid = threadIdx.x;
    const int wv = tid >> 6, lane = tid & 63;
    const int l15 = lane & 15, l4 = lane >> 4;
    const int fr = l15, fc = l4 * 8;

    f32x4 acc[4][4] = {};

    auto stage = [&](int buf, int t) {
        const int kk = kbase + t * 32;
#pragma unroll
        for (int c = 0; c < 2; ++c) {
            int sub = wv * 2 + c;
            gl16(Ap + (size_t)(bm + sub * 16 + fr) * 4096 + kk + fc, &As[buf][sub * 512]);
            gl16(Bp + (size_t)(sub * 16 + fr) * 4096 + kk + fc, &Bs[buf][sub * 512]);
        }
    };
    auto compute = [&](int buf) {
        f16x8 xf[4], yf[4];
#pragma unroll
        for (int m = 0; m < 4; ++m)
            xf[m] = *(f16x8*)&As[buf][((wv >> 1) * 4 + m) * 512 + lane * 8];
#pragma unroll
        for (int n = 0; n < 4; ++n)
            yf[n] = *(f16x8*)&Bs[buf][((wv & 1) * 4 + n) * 512 + lane * 8];
#pragma unroll
        for (int m = 0; m < 4; ++m)
#pragma unroll
            for (int n = 0; n < 4; ++n)
                acc[m][n] = __builtin_amdgcn_mfma_f32_16x16x32_f16(xf[m], yf[n], acc[m][n], 0, 0, 0);
    };

    stage(0, 0);
    __syncthreads();
    for (int t = 0; t < 64; ++t) {
        const int cur = t & 1;
        if (t + 1 < 64) stage(cur ^ 1, t + 1);
        compute(cur);
        __syncthreads();
    }

    float* Pc = P + (size_t)ck * 1024 * NW;
#pragma unroll
    for (int m = 0; m < 4; ++m)
#pragma unroll
        for (int n = 0; n < 4; ++n)
#pragma unroll
            for (int r = 0; r < 4; ++r) {
                int row = bm + (wv >> 1) * 64 + m * 16 + l4 * 4 + r;
                int col = bncol + (wv & 1) * 64 + n * 16 + l15;
                Pc[(size_t)row * NW + col] = acc[m][n][r];
            }
}

// ---------------- combine + sample (N=4096 logits) ----------------
template<int EPI, int NC>
__global__ __launch_bounds__(256) void combine_h(
    const float* __restrict__ P, const float* __restrict__ bias,
    short* __restrict__ O0, short* __restrict__ O1,
    uint32_t k0, uint32_t k1)
{
    size_t e0 = ((size_t)blockIdx.x * 256 + threadIdx.x) * 8;
    f32x4 s0 = {}, s1 = {};
#pragma unroll
    for (int c = 0; c < NC; ++c) {
        const float* p = P + (size_t)c * 4194304 + e0;
        s0 += *(const f32x4*)p;
        s1 += *(const f32x4*)(p + 4);
    }
    int col = (int)(e0 & 4095);
    short o[8];
#pragma unroll
    for (int j = 0; j < 8; ++j) {
        float v = ((j < 4) ? s0[j] : s1[j - 4]) + bias[col + j];
        float pr = sigmoidf_(v);
        float u = tf_uniform01(k0, k1, (uint32_t)(e0 + j));
        o[j] = (u < pr) ? F16_ONE : (short)0;
    }
    *(bf16x8*)&O0[e0] = *(bf16x8*)o;
    if (EPI == 1) *(bf16x8*)&O1[e0] = *(bf16x8*)o;
}

// ---------------- combine + sample (dual N=8192: h2 | pv-sign) ----------------
__global__ __launch_bounds__(256) void combine_dual(
    const float* __restrict__ P,
    const float* __restrict__ b_h2, const float* __restrict__ b_v,
    const float* __restrict__ occ,
    short* __restrict__ h2n, short* __restrict__ vneg,
    uint32_t kb0, uint32_t kb1, uint32_t kc0, uint32_t kc1)
{
    size_t e0 = ((size_t)blockIdx.x * 256 + threadIdx.x) * 8;
    int row = (int)(e0 >> 13);
    int cl  = (int)(e0 & 8191);
    f32x4 s0 = {}, s1 = {};
#pragma unroll
    for (int c = 0; c < 2; ++c) {
        const float* p = P + (size_t)c * 8388608 + e0;
        s0 += *(const f32x4*)p;
        s1 += *(const f32x4*)(p + 4);
    }
    short o[8];
    if (cl < 4096) {
#pragma unroll
        for (int j = 0; j < 8; ++j) {
            float v = ((j < 4) ? s0[j] : s1[j - 4]) + b_h2[cl + j];
            float pr = sigmoidf_(v);
            size_t e = (size_t)row * 4096 + cl + j;
            float u = tf_uniform01(kb0, kb1, (uint32_t)e);
            o[j] = (u < pr) ? F16_ONE : (short)0;
        }
        *(bf16x8*)&h2n[(size_t)row * 4096 + cl] = *(bf16x8*)o;
    } else {
        int v0 = cl - 4096;
#pragma unroll
        for (int j = 0; j < 8; ++j) {
            int vcol = v0 + j;
            if (vcol & 1) {
                int s = (vcol - 1) >> 1;
                float v = ((j < 4) ? s0[j] : s1[j - 4]) + b_v[vcol];
                float pr = sigmoidf_(v);
                float u = tf_uniform01(kc0, kc1, (uint32_t)(row * 2048 + s));
                o[j] = (u < pr) ? F16_ONE : (short)0;
            } else {
                o[j] = (occ[(size_t)row * 2048 + (vcol >> 1)] != 0.0f) ? F16_ONE : (short)0;
            }
        }
        *(bf16x8*)&vneg[(size_t)row * 4096 + v0] = *(bf16x8*)o;
    }
}

// =====================================================================
// Gradient GEMM (exact): Out[i,j] = (sum_b Xn Yn - Xp Yp)/1024, fp16 states.
// tile 128x128, 256 threads = 4 waves (64x64 each); unchanged.
// =====================================================================
template<int W1MODE>
__global__ __launch_bounds__(256) void grad_mm(
    const short* __restrict__ Xn, const short* __restrict__ Yn,
    const short* __restrict__ Xp, const short* __restrict__ Yp_bf,
    const float* __restrict__ Yp_f32,
    float* __restrict__ Out)
{
    __shared__ __align__(1024) short Xs[2][8 * 512];
    __shared__ __align__(1024) short Ys[2][8 * 512];

    const int tid = threadIdx.x;
    const int bi = blockIdx.y * 128, bj = blockIdx.x * 128;
    const int wv = tid >> 6, lane = tid & 63;
    const int wr = (wv >> 1) * 64, wc = (wv & 1) * 64;
    const int l15 = lane & 15, l4 = lane >> 4;

    const int cg = (tid & 31) * 4;
    const int kg = tid >> 5;
    const int qsub = (tid & 31) >> 2;
    const int koff = (kg >> 1) * 128 + (kg & 1) * 4;

    f32x4 acc[4][4] = {};
    short xr[4][4];
    short yr[4][4];

    auto loadT = [&](int bt) {
        const bool neg = bt < 32;
        const int b0 = (bt & 31) * 32;
        const short* X = neg ? Xn : Xp;
#pragma unroll
        for (int i = 0; i < 4; ++i)
            *(bf16x4*)xr[i] = *(const bf16x4*)(X + (size_t)(b0 + kg * 4 + i) * NH + bi + cg);
        if (W1MODE) {
            if (neg) {
#pragma unroll
                for (int i = 0; i < 4; ++i) {
                    bf16x8 v = *(const bf16x8*)(Yn + (size_t)(b0 + kg * 4 + i) * NV + 2 * (bj + cg));
                    yr[i][0] = v[1]; yr[i][1] = v[3]; yr[i][2] = v[5]; yr[i][3] = v[7];
                }
            } else {
#pragma unroll
                for (int i = 0; i < 4; ++i) {
                    const float* p = Yp_f32 + (size_t)(b0 + kg * 4 + i) * NV + 2 * (bj + cg);
                    f32x4 a = *(const f32x4*)p;
                    f32x4 b = *(const f32x4*)(p + 4);
                    yr[i][0] = (a[1] != 0.0f) ? F16_NEG1 : (short)0;
                    yr[i][1] = (a[3] != 0.0f) ? F16_NEG1 : (short)0;
                    yr[i][2] = (b[1] != 0.0f) ? F16_NEG1 : (short)0;
                    yr[i][3] = (b[3] != 0.0f) ? F16_NEG1 : (short)0;
                }
            }
        } else {
            const short* Y = neg ? Yn : Yp_bf;
            const short sx = neg ? (short)0 : (short)0x8000;
#pragma unroll
            for (int i = 0; i < 4; ++i) {
                bf16x4 v = *(const bf16x4*)(Y + (size_t)(b0 + kg * 4 + i) * NH + bj + cg);
#pragma unroll
                for (int j = 0; j < 4; ++j) yr[i][j] = (short)(v[j] ^ sx);
            }
        }
    };
    auto writeT = [&](int buf) {
#pragma unroll
        for (int j = 0; j < 4; ++j) {
            int r = (tid & 3) * 4 + j;
            int off = qsub * 512 + koff + ((r ^ qsub) & 15) * 8;
            short wx[4] = {xr[0][j], xr[1][j], xr[2][j], xr[3][j]};
            short wy[4] = {yr[0][j], yr[1][j], yr[2][j], yr[3][j]};
            *(bf16x4*)&Xs[buf][off] = *(bf16x4*)wx;
            *(bf16x4*)&Ys[buf][off] = *(bf16x4*)wy;
        }
    };

    loadT(0);
    writeT(0);
    __syncthreads();

    for (int bt = 0; bt < 64; ++bt) {
        const int cur = bt & 1;
        if (bt + 1 < 64) loadT(bt + 1);

        f16x8 xf[4], yf[4];
#pragma unroll
        for (int m = 0; m < 4; ++m) {
            int sm = (wv >> 1) * 4 + m;
            xf[m] = *(f16x8*)&Xs[cur][sm * 512 + l4 * 128 + ((l15 ^ sm) & 15) * 8];
        }
#pragma unroll
        for (int n = 0; n < 4; ++n) {
            int sn = (wv & 1) * 4 + n;
            yf[n] = *(f16x8*)&Ys[cur][sn * 512 + l4 * 128 + ((l15 ^ sn) & 15) * 8];
        }
#pragma unroll
        for (int m = 0; m < 4; ++m)
#pragma unroll
            for (int n = 0; n < 4; ++n)
                acc[m][n] = __builtin_amdgcn_mfma_f32_16x16x32_f16(xf[m], yf[n], acc[m][n], 0, 0, 0);

        if (bt + 1 < 64) writeT(cur ^ 1);
        __syncthreads();
    }

    const float invB = 1.0f / 1024.0f;
#pragma unroll
    for (int m = 0; m < 4; ++m)
#pragma unroll
        for (int n = 0; n < 4; ++n)
#pragma unroll
            for (int r = 0; r < 4; ++r) {
                int i_ = bi + wr + m * 16 + l4 * 4 + r;
                int j_ = bj + wc + n * 16 + l15;
                if (W1MODE) {
                    Out[(size_t)i_ * NV + 2 * j_ + 1] = acc[m][n][r] * invB;
                    Out[(size_t)i_ * NV + 2 * j_]     = 0.0f;
                } else {
                    Out[(size_t)i_ * NH + j_] = acc[m][n][r] * invB;
                }
            }
}

// ---------------- small kernels ----------------
__global__ void cvt_kernel(const float* __restrict__ in, short* __restrict__ out, int n)
{
    int e = blockIdx.x * 256 + threadIdx.x;
    if (e < n) out[e] = (in[e] != 0.0f) ? F16_ONE : (short)0;
}

__global__ void dbv_fast(const float* __restrict__ vdata, const short* __restrict__ vneg,
                         float* __restrict__ out)
{
    __shared__ float part[4][64];
    int c = threadIdx.x & 63, rg = threadIdx.x >> 6;
    int s = blockIdx.x * 64 + c;
    float acc = 0.0f;
    for (int b = rg; b < B_SZ; b += 4)
        acc += ((vneg[(size_t)b * NV + 2 * s + 1] != 0) ? 1.0f : 0.0f)
             - vdata[(size_t)b * NV + 2 * s + 1];
    part[rg][c] = acc;
    __syncthreads();
    if (rg == 0) {
        out[2 * s + 1] = (part[0][c] + part[1][c] + part[2][c] + part[3][c]) * (1.0f / 1024.0f);
        out[2 * s] = 0.0f;
    }
}

__global__ void dbh_fast(const short* __restrict__ Xp, const short* __restrict__ Xn,
                         float* __restrict__ out)
{
    __shared__ int part[4][64];
    int c = threadIdx.x & 63, rg = threadIdx.x >> 6;
    int j = blockIdx.x * 64 + c;
    int acc = 0;
    for (int b = rg; b < B_SZ; b += 4)
        acc += (int)(Xn[(size_t)b * NH + j] != 0) - (int)(Xp[(size_t)b * NH + j] != 0);
    part[rg][c] = acc;
    __syncthreads();
    if (rg == 0)
        out[j] = (float)(part[0][c] + part[1][c] + part[2][c] + part[3][c]) * (1.0f / 1024.0f);
}

__global__ void zero_kernel(unsigned* p) { *p = 0u; }

__global__ void loss_count2(const float* __restrict__ vdata,
                            const short* __restrict__ vneg, unsigned* cnt)
{
    __shared__ int part[4];
    int t = blockIdx.x * 256 + threadIdx.x;
    int local = 0;
#pragma unroll
    for (int it = 0; it < 8; ++it) {
        int e = t + it * 262144;
        int b = e >> 11, s = e & 2047;
        float st = vdata[(size_t)b * NV + 2 * s + 1];
        float sp = (vneg[(size_t)b * NV + 2 * s + 1] != 0) ? 1.0f : 0.0f;
        local += (st != sp) ? 1 : 0;
    }
#pragma unroll
    for (int off = 32; off; off >>= 1) local += __shfl_down(local, off, 64);
    if ((threadIdx.x & 63) == 0) part[threadIdx.x >> 6] = local;
    __syncthreads();
    if (threadIdx.x == 0)
        atomicAdd(cnt, (unsigned)(part[0] + part[1] + part[2] + part[3]));
}

__global__ void loss_final_kernel(const unsigned* cnt, float* out, float lp, float lm)
{
    float mis = (float)(*cnt);
    float mat = 2097152.0f - mis;
    out[0] = -((mat * lp + mis * lm) * (1.0f / 2097152.0f));
}

// ---------------- host ----------------
extern "C" void kernel_launch(void* const* d_in, const int* in_sizes, int n_in,
                              void* d_out, int out_size, void* d_ws, size_t ws_size,
                              hipStream_t stream)
{
    (void)in_sizes; (void)n_in; (void)out_size; (void)ws_size;
    const float* v_data = (const float*)d_in[0];
    const float* occ    = (const float*)d_in[1];
    const float* W1     = (const float*)d_in[2];
    const float* b_v    = (const float*)d_in[3];
    const float* b_h1   = (const float*)d_in[4];
    const float* W2     = (const float*)d_in[5];
    const float* b_h2   = (const float*)d_in[6];
    float* out = (float*)d_out;

    char* w = (char*)d_ws;
    short* vneg = (short*)w;                            // 5 x 8 MB fp16 states
    short* h1d  = vneg + (size_t)B_SZ * NV;
    short* h2d  = h1d  + (size_t)B_SZ * NH;
    short* h1c  = h2d  + (size_t)B_SZ * NH;
    short* h2n  = h1c  + (size_t)B_SZ * NH;
    float* P    = (float*)(h2n + (size_t)B_SZ * NH);    // 64 MB partials
    unsigned* cnt = (unsigned*)(P + (size_t)4 * 1024 * 4096);

    // d_out doubles as fp16 weight scratch (128 MB of the 134 MB output;
    // fully overwritten by gradient kernels afterwards).
    short* W1f = (short*)(((uintptr_t)(out + 1) + 15) & ~(uintptr_t)15);
    short* W1T = W1f + (size_t)NH * NV;
    short* W2f = W1T + (size_t)NH * NV;
    short* W2T = W2f + (size_t)NH * NH;

    // ---- JAX key derivation ----
    const uint32_t r0 = 0u, r1 = 42u;
    uint32_t kp1a, kp1b, kp2a, kp2b, kfa, kfb, kla, klb;
    tf2x32(r0, r1, 0u, 0u, kp1a, kp1b);
    tf2x32(r0, r1, 0u, 1u, kp2a, kp2b);
    tf2x32(r0, r1, 0u, 2u, kfa, kfb);
    tf2x32(r0, r1, 0u, 3u, kla, klb);
    uint32_t kaA[2], kaB[2], kbA[2], kbB[2], kcA[2], kcB[2];
    for (int i = 0; i < 2; ++i) {
        uint32_t fa, fb;
        tf2x32(kla, klb, 0u, (uint32_t)i, fa, fb);
        tf2x32(fa, fb, 0u, 0u, kaA[i], kaB[i]);
        tf2x32(fa, fb, 0u, 1u, kbA[i], kbB[i]);
        tf2x32(fa, fb, 0u, 2u, kcA[i], kcB[i]);
    }

    const int T = 256;
    const int NELEM = B_SZ * NH;
    dim3 gTr(64, 64);

    conv_tr<<<gTr, 256, 0, stream>>>(W1, W1f, W1T);
    conv_tr<<<gTr, 256, 0, stream>>>(W2, W2f, W2T);

    cvt_kernel<<<NELEM / T, T, 0, stream>>>(v_data, vneg, NELEM);

    // positive phase
    mm_chunk<0><<<512, 256, 0, stream>>>(vneg, nullptr, W1f, nullptr, P);
    combine_h<0, 2><<<2048, 256, 0, stream>>>(P, b_h1, h1d, nullptr, kp1a, kp1b);
    mm_chunk<0><<<512, 256, 0, stream>>>(h1d, nullptr, W2f, nullptr, P);
    combine_h<1, 2><<<2048, 256, 0, stream>>>(P, b_h2, h2d, h2n, kp2a, kp2b);

    // Gibbs loop (k = 2)
    for (int i = 0; i < 2; ++i) {
        mm_chunk<1><<<1024, 256, 0, stream>>>(vneg, h2n, W1f, W2T, P);
        combine_h<0, 4><<<2048, 256, 0, stream>>>(P, b_h1, h1c, nullptr, kaA[i], kaB[i]);
        mm_chunk<2><<<1024, 256, 0, stream>>>(h1c, nullptr, W2f, W1T, P);
        combine_dual<<<4096, 256, 0, stream>>>(P, b_h2, b_v, occ, h2n, vneg,
                                               kbA[i], kbB[i], kcA[i], kcB[i]);
    }

    // final hidden refresh
    mm_chunk<1><<<1024, 256, 0, stream>>>(vneg, h2n, W1f, W2T, P);
    combine_h<0, 4><<<2048, 256, 0, stream>>>(P, b_h1, h1c, nullptr, kfa, kfb);

    // outputs (weight scratch dead after this point)
    float* dW1o  = out + 1;
    float* dbvo  = dW1o + (size_t)NH * NV;
    float* dbh1o = dbvo + NV;
    float* dW2o  = dbh1o + NH;
    float* dbh2o = dW2o + (size_t)NH * NH;

    grad_mm<1><<<dim3(NSGN / 128, NH / 128), T, 0, stream>>>(h1c, vneg, h1d, (short*)nullptr, v_data, dW1o);
    grad_mm<0><<<dim3(NH / 128, NH / 128), T, 0, stream>>>(h1c, h2n, h1d, h2d, (const float*)nullptr, dW2o);
    dbv_fast<<<NSGN / 64, T, 0, stream>>>(v_data, vneg, dbvo);
    dbh_fast<<<NH / 64, T, 0, stream>>>(h1d, h1c, dbh1o);
    dbh_fast<<<NH / 64, T, 0, stream>>>(h2d, h2n, dbh2o);

    zero_kernel<<<1, 1, 0, stream>>>(cnt);
    loss_count2<<<1024, T, 0, stream>>>(v_data, vneg, cnt);
    loss_final_kernel<<<1, 1, 0, stream>>>(cnt, out, logf(1.0f + 1e-7f), logf(1e-7f));
}

// Round 15
// 1262.543 us; speedup vs baseline: 1.1491x; 1.1491x over previous
//
#include <hip/hip_runtime.h>
#include <stdint.h>
#include <math.h>

#define B_SZ 1024
#define NV   4096
#define NH   4096
#define NSGN 2048

typedef short bf16x8 __attribute__((ext_vector_type(8)));
typedef short bf16x4 __attribute__((ext_vector_type(4)));
typedef float f32x4  __attribute__((ext_vector_type(4)));
typedef _Float16 f16x8 __attribute__((ext_vector_type(8)));

#define F16_ONE  ((short)0x3C00)
#define F16_NEG1 ((short)0xBC00)

// ---------------- threefry2x32 (JAX-compatible, 20 rounds) ----------------
__host__ __device__ __forceinline__ void tf2x32(uint32_t k0, uint32_t k1,
                                                uint32_t x0, uint32_t x1,
                                                uint32_t& o0, uint32_t& o1)
{
    uint32_t k2 = k0 ^ k1 ^ 0x1BD11BDAu;
#define TFR(r) { x0 += x1; x1 = (x1 << (r)) | (x1 >> (32 - (r))); x1 ^= x0; }
    x0 += k0; x1 += k1;
    TFR(13) TFR(15) TFR(26) TFR(6)
    x0 += k1; x1 += k2 + 1u;
    TFR(17) TFR(29) TFR(16) TFR(24)
    x0 += k2; x1 += k0 + 2u;
    TFR(13) TFR(15) TFR(26) TFR(6)
    x0 += k0; x1 += k1 + 3u;
    TFR(17) TFR(29) TFR(16) TFR(24)
    x0 += k1; x1 += k2 + 4u;
    TFR(13) TFR(15) TFR(26) TFR(6)
    x0 += k2; x1 += k0 + 5u;
#undef TFR
    o0 = x0; o1 = x1;
}

__device__ __forceinline__ float tf_uniform01(uint32_t k0, uint32_t k1, uint32_t idx)
{
    uint32_t a, b;
    tf2x32(k0, k1, 0u, idx, a, b);
    uint32_t bits = a ^ b;
    uint32_t fb = (bits >> 9) | 0x3F800000u;
    return __uint_as_float(fb) - 1.0f;
}

__device__ __forceinline__ float sigmoidf_(float x)
{
    if (x >= 0.0f) { float e = expf(-x); return 1.0f / (1.0f + e); }
    float e = expf(x); return e / (1.0f + e);
}

__device__ __forceinline__ void gl16(const void* g, void* l)
{
    __builtin_amdgcn_global_load_lds((const __attribute__((address_space(1))) void*)g,
                                     (__attribute__((address_space(3))) void*)l, 16, 0, 0);
}

// ---------------- weight precompute: fp32 -> fp16 direct + transposed ----------------
__global__ __launch_bounds__(256) void conv_tr(const float* __restrict__ W,
                                               short* __restrict__ Wf,
                                               short* __restrict__ Wt)
{
    __shared__ short t[64][65];
    const int bx = blockIdx.x * 64;
    const int by = blockIdx.y * 64;
    const int r0 = threadIdx.x >> 4;
    const int c0 = (threadIdx.x & 15) * 4;
#pragma unroll
    for (int i = 0; i < 4; ++i) {
        int row = by + r0 + i * 16;
        f32x4 v = *(const f32x4*)(W + (size_t)row * 4096 + bx + c0);
        short h[4];
#pragma unroll
        for (int j = 0; j < 4; ++j) {
            union { _Float16 f; short s; } u;
            u.f = (_Float16)v[j];
            h[j] = u.s;
        }
        *(bf16x4*)(Wf + (size_t)row * 4096 + bx + c0) = *(bf16x4*)h;
#pragma unroll
        for (int j = 0; j < 4; ++j) t[c0 + j][r0 + i * 16] = h[j];
    }
    __syncthreads();
#pragma unroll
    for (int i = 0; i < 4; ++i) {
        int orow = r0 + i * 16;
        short o[4] = { t[orow][c0], t[orow][c0 + 1], t[orow][c0 + 2], t[orow][c0 + 3] };
        *(bf16x4*)(Wt + (size_t)(bx + orow) * 4096 + by + c0) = *(bf16x4*)o;
    }
}

// =====================================================================
// Chunk GEMM, 256(M) x 128(N) tile (halves B re-staging vs 128x128),
// BK=32, 512 thr = 8 waves (4M x 2N of 64x64, 16 MFMA/step each),
// 48 KB LDS dbuf, 3 gl16/wave/step (2 A + 1 B, fragment-order source).
// Writes f32 partials P[ck][1024][NW]. All grids 512 = 2 blocks/CU.
//  MODE 0: K=4096 -> 4 chunks of 1024 (A0,B0), 32 steps.
//  MODE 1: K=8192 concat -> 4 chunks of 2048 (A0,B0 then A1,B1), 64 steps.
//  MODE 2: dual-N 8192 (64 panels: B0=W2f pn<32, B1=W1T), K=4096 ->
//          2 chunks of 2048, 64 steps.
// XCD-swizzled (pn fastest within XCD).
// =====================================================================
template<int MODE>
__global__ __launch_bounds__(512, 2) void mm_chunk(
    const short* __restrict__ A0, const short* __restrict__ A1,
    const short* __restrict__ B0, const short* __restrict__ B1,
    float* __restrict__ P)
{
    __shared__ __align__(1024) short As[2][16 * 512];
    __shared__ __align__(1024) short Bs[2][8 * 512];

    const int bid = blockIdx.x;
    const int xcd = bid & 7, slot = bid >> 3;

    int bm, bncol, ck, kbase, NW;
    const short* Ap;
    const short* Bp;
    if (MODE == 2) {
        int pn = xcd * 8 + (slot & 7);          // 0..63
        bm = ((slot >> 3) & 3) * 256;
        ck = slot >> 5;                         // 0..1
        kbase = ck * 2048;
        Ap = A0;
        Bp = (pn < 32) ? (B0 + (size_t)pn * 128 * 4096)
                       : (B1 + (size_t)(pn - 32) * 128 * 4096);
        bncol = pn * 128;
        NW = 8192;
    } else {
        int pn = xcd * 4 + (slot & 3);          // 0..31
        bm = ((slot >> 2) & 3) * 256;
        ck = slot >> 4;                         // 0..3
        if (MODE == 1) {
            if (ck >= 2) { Ap = A1; Bp = B1 + (size_t)pn * 128 * 4096; kbase = (ck - 2) * 2048; }
            else         { Ap = A0; Bp = B0 + (size_t)pn * 128 * 4096; kbase = ck * 2048; }
        } else {
            Ap = A0; Bp = B0 + (size_t)pn * 128 * 4096; kbase = ck * 1024;
        }
        bncol = pn * 128;
        NW = 4096;
    }

    const int NT = (MODE == 0) ? 32 : 64;

    const int tid = threadIdx.x;
    const int wv = tid >> 6, lane = tid & 63;
    const int l15 = lane & 15, l4 = lane >> 4;
    const int fr = l15, fc = l4 * 8;
    const int wm = wv >> 1, wn = wv & 1;        // 4(M) x 2(N) wave grid

    f32x4 acc[4][4] = {};

    auto stage = [&](int buf, int t) {
        const int kk = kbase + t * 32;
        // A: 16 subtiles, 2 per wave
        gl16(Ap + (size_t)(bm + (wv * 2 + 0) * 16 + fr) * 4096 + kk + fc, &As[buf][(wv * 2 + 0) * 512]);
        gl16(Ap + (size_t)(bm + (wv * 2 + 1) * 16 + fr) * 4096 + kk + fc, &As[buf][(wv * 2 + 1) * 512]);
        // B: 8 subtiles, 1 per wave
        gl16(Bp + (size_t)(wv * 16 + fr) * 4096 + kk + fc, &Bs[buf][wv * 512]);
    };
    auto compute = [&](int buf) {
        f16x8 xf[4], yf[4];
#pragma unroll
        for (int m = 0; m < 4; ++m)
            xf[m] = *(f16x8*)&As[buf][(wm * 4 + m) * 512 + lane * 8];
#pragma unroll
        for (int n = 0; n < 4; ++n)
            yf[n] = *(f16x8*)&Bs[buf][(wn * 4 + n) * 512 + lane * 8];
#pragma unroll
        for (int m = 0; m < 4; ++m)
#pragma unroll
            for (int n = 0; n < 4; ++n)
                acc[m][n] = __builtin_amdgcn_mfma_f32_16x16x32_f16(xf[m], yf[n], acc[m][n], 0, 0, 0);
    };

    stage(0, 0);
    __syncthreads();
    for (int t = 0; t < NT; ++t) {
        const int cur = t & 1;
        if (t + 1 < NT) stage(cur ^ 1, t + 1);
        compute(cur);
        __syncthreads();
    }

    float* Pc = P + (size_t)ck * 1024 * NW;
#pragma unroll
    for (int m = 0; m < 4; ++m)
#pragma unroll
        for (int n = 0; n < 4; ++n)
#pragma unroll
            for (int r = 0; r < 4; ++r) {
                int row = bm + wm * 64 + m * 16 + l4 * 4 + r;
                int col = bncol + wn * 64 + n * 16 + l15;
                Pc[(size_t)row * NW + col] = acc[m][n][r];
            }
}

// ---------------- combine + sample (N=4096 logits) ----------------
template<int EPI, int NC>
__global__ __launch_bounds__(256) void combine_h(
    const float* __restrict__ P, const float* __restrict__ bias,
    short* __restrict__ O0, short* __restrict__ O1,
    uint32_t k0, uint32_t k1)
{
    size_t e0 = ((size_t)blockIdx.x * 256 + threadIdx.x) * 8;
    f32x4 s0 = {}, s1 = {};
#pragma unroll
    for (int c = 0; c < NC; ++c) {
        const float* p = P + (size_t)c * 4194304 + e0;
        s0 += *(const f32x4*)p;
        s1 += *(const f32x4*)(p + 4);
    }
    int col = (int)(e0 & 4095);
    short o[8];
#pragma unroll
    for (int j = 0; j < 8; ++j) {
        float v = ((j < 4) ? s0[j] : s1[j - 4]) + bias[col + j];
        float pr = sigmoidf_(v);
        float u = tf_uniform01(k0, k1, (uint32_t)(e0 + j));
        o[j] = (u < pr) ? F16_ONE : (short)0;
    }
    *(bf16x8*)&O0[e0] = *(bf16x8*)o;
    if (EPI == 1) *(bf16x8*)&O1[e0] = *(bf16x8*)o;
}

// ---------------- combine + sample (dual N=8192: h2 | pv-sign) ----------------
__global__ __launch_bounds__(256) void combine_dual(
    const float* __restrict__ P,
    const float* __restrict__ b_h2, const float* __restrict__ b_v,
    const float* __restrict__ occ,
    short* __restrict__ h2n, short* __restrict__ vneg,
    uint32_t kb0, uint32_t kb1, uint32_t kc0, uint32_t kc1)
{
    size_t e0 = ((size_t)blockIdx.x * 256 + threadIdx.x) * 8;
    int row = (int)(e0 >> 13);
    int cl  = (int)(e0 & 8191);
    f32x4 s0 = {}, s1 = {};
#pragma unroll
    for (int c = 0; c < 2; ++c) {
        const float* p = P + (size_t)c * 8388608 + e0;
        s0 += *(const f32x4*)p;
        s1 += *(const f32x4*)(p + 4);
    }
    short o[8];
    if (cl < 4096) {
#pragma unroll
        for (int j = 0; j < 8; ++j) {
            float v = ((j < 4) ? s0[j] : s1[j - 4]) + b_h2[cl + j];
            float pr = sigmoidf_(v);
            size_t e = (size_t)row * 4096 + cl + j;
            float u = tf_uniform01(kb0, kb1, (uint32_t)e);
            o[j] = (u < pr) ? F16_ONE : (short)0;
        }
        *(bf16x8*)&h2n[(size_t)row * 4096 + cl] = *(bf16x8*)o;
    } else {
        int v0 = cl - 4096;
#pragma unroll
        for (int j = 0; j < 8; ++j) {
            int vcol = v0 + j;
            if (vcol & 1) {
                int s = (vcol - 1) >> 1;
                float v = ((j < 4) ? s0[j] : s1[j - 4]) + b_v[vcol];
                float pr = sigmoidf_(v);
                float u = tf_uniform01(kc0, kc1, (uint32_t)(row * 2048 + s));
                o[j] = (u < pr) ? F16_ONE : (short)0;
            } else {
                o[j] = (occ[(size_t)row * 2048 + (vcol >> 1)] != 0.0f) ? F16_ONE : (short)0;
            }
        }
        *(bf16x8*)&vneg[(size_t)row * 4096 + v0] = *(bf16x8*)o;
    }
}

// =====================================================================
// Gradient GEMM (exact): Out[i,j] = (sum_b Xn Yn - Xp Yp)/1024, fp16 states.
// tile 128x128, 256 threads = 4 waves (64x64 each); unchanged.
// =====================================================================
template<int W1MODE>
__global__ __launch_bounds__(256) void grad_mm(
    const short* __restrict__ Xn, const short* __restrict__ Yn,
    const short* __restrict__ Xp, const short* __restrict__ Yp_bf,
    const float* __restrict__ Yp_f32,
    float* __restrict__ Out)
{
    __shared__ __align__(1024) short Xs[2][8 * 512];
    __shared__ __align__(1024) short Ys[2][8 * 512];

    const int tid = threadIdx.x;
    const int bi = blockIdx.y * 128, bj = blockIdx.x * 128;
    const int wv = tid >> 6, lane = tid & 63;
    const int wr = (wv >> 1) * 64, wc = (wv & 1) * 64;
    const int l15 = lane & 15, l4 = lane >> 4;

    const int cg = (tid & 31) * 4;
    const int kg = tid >> 5;
    const int qsub = (tid & 31) >> 2;
    const int koff = (kg >> 1) * 128 + (kg & 1) * 4;

    f32x4 acc[4][4] = {};
    short xr[4][4];
    short yr[4][4];

    auto loadT = [&](int bt) {
        const bool neg = bt < 32;
        const int b0 = (bt & 31) * 32;
        const short* X = neg ? Xn : Xp;
#pragma unroll
        for (int i = 0; i < 4; ++i)
            *(bf16x4*)xr[i] = *(const bf16x4*)(X + (size_t)(b0 + kg * 4 + i) * NH + bi + cg);
        if (W1MODE) {
            if (neg) {
#pragma unroll
                for (int i = 0; i < 4; ++i) {
                    bf16x8 v = *(const bf16x8*)(Yn + (size_t)(b0 + kg * 4 + i) * NV + 2 * (bj + cg));
                    yr[i][0] = v[1]; yr[i][1] = v[3]; yr[i][2] = v[5]; yr[i][3] = v[7];
                }
            } else {
#pragma unroll
                for (int i = 0; i < 4; ++i) {
                    const float* p = Yp_f32 + (size_t)(b0 + kg * 4 + i) * NV + 2 * (bj + cg);
                    f32x4 a = *(const f32x4*)p;
                    f32x4 b = *(const f32x4*)(p + 4);
                    yr[i][0] = (a[1] != 0.0f) ? F16_NEG1 : (short)0;
                    yr[i][1] = (a[3] != 0.0f) ? F16_NEG1 : (short)0;
                    yr[i][2] = (b[1] != 0.0f) ? F16_NEG1 : (short)0;
                    yr[i][3] = (b[3] != 0.0f) ? F16_NEG1 : (short)0;
                }
            }
        } else {
            const short* Y = neg ? Yn : Yp_bf;
            const short sx = neg ? (short)0 : (short)0x8000;
#pragma unroll
            for (int i = 0; i < 4; ++i) {
                bf16x4 v = *(const bf16x4*)(Y + (size_t)(b0 + kg * 4 + i) * NH + bj + cg);
#pragma unroll
                for (int j = 0; j < 4; ++j) yr[i][j] = (short)(v[j] ^ sx);
            }
        }
    };
    auto writeT = [&](int buf) {
#pragma unroll
        for (int j = 0; j < 4; ++j) {
            int r = (tid & 3) * 4 + j;
            int off = qsub * 512 + koff + ((r ^ qsub) & 15) * 8;
            short wx[4] = {xr[0][j], xr[1][j], xr[2][j], xr[3][j]};
            short wy[4] = {yr[0][j], yr[1][j], yr[2][j], yr[3][j]};
            *(bf16x4*)&Xs[buf][off] = *(bf16x4*)wx;
            *(bf16x4*)&Ys[buf][off] = *(bf16x4*)wy;
        }
    };

    loadT(0);
    writeT(0);
    __syncthreads();

    for (int bt = 0; bt < 64; ++bt) {
        const int cur = bt & 1;
        if (bt + 1 < 64) loadT(bt + 1);

        f16x8 xf[4], yf[4];
#pragma unroll
        for (int m = 0; m < 4; ++m) {
            int sm = (wv >> 1) * 4 + m;
            xf[m] = *(f16x8*)&Xs[cur][sm * 512 + l4 * 128 + ((l15 ^ sm) & 15) * 8];
        }
#pragma unroll
        for (int n = 0; n < 4; ++n) {
            int sn = (wv & 1) * 4 + n;
            yf[n] = *(f16x8*)&Ys[cur][sn * 512 + l4 * 128 + ((l15 ^ sn) & 15) * 8];
        }
#pragma unroll
        for (int m = 0; m < 4; ++m)
#pragma unroll
            for (int n = 0; n < 4; ++n)
                acc[m][n] = __builtin_amdgcn_mfma_f32_16x16x32_f16(xf[m], yf[n], acc[m][n], 0, 0, 0);

        if (bt + 1 < 64) writeT(cur ^ 1);
        __syncthreads();
    }

    const float invB = 1.0f / 1024.0f;
#pragma unroll
    for (int m = 0; m < 4; ++m)
#pragma unroll
        for (int n = 0; n < 4; ++n)
#pragma unroll
            for (int r = 0; r < 4; ++r) {
                int i_ = bi + wr + m * 16 + l4 * 4 + r;
                int j_ = bj + wc + n * 16 + l15;
                if (W1MODE) {
                    Out[(size_t)i_ * NV + 2 * j_ + 1] = acc[m][n][r] * invB;
                    Out[(size_t)i_ * NV + 2 * j_]     = 0.0f;
                } else {
                    Out[(size_t)i_ * NH + j_] = acc[m][n][r] * invB;
                }
            }
}

// ---------------- small kernels ----------------
__global__ void cvt_kernel(const float* __restrict__ in, short* __restrict__ out, int n)
{
    int e = blockIdx.x * 256 + threadIdx.x;
    if (e < n) out[e] = (in[e] != 0.0f) ? F16_ONE : (short)0;
}

__global__ void dbv_fast(const float* __restrict__ vdata, const short* __restrict__ vneg,
                         float* __restrict__ out)
{
    __shared__ float part[4][64];
    int c = threadIdx.x & 63, rg = threadIdx.x >> 6;
    int s = blockIdx.x * 64 + c;
    float acc = 0.0f;
    for (int b = rg; b < B_SZ; b += 4)
        acc += ((vneg[(size_t)b * NV + 2 * s + 1] != 0) ? 1.0f : 0.0f)
             - vdata[(size_t)b * NV + 2 * s + 1];
    part[rg][c] = acc;
    __syncthreads();
    if (rg == 0) {
        out[2 * s + 1] = (part[0][c] + part[1][c] + part[2][c] + part[3][c]) * (1.0f / 1024.0f);
        out[2 * s] = 0.0f;
    }
}

__global__ void dbh_fast(const short* __restrict__ Xp, const short* __restrict__ Xn,
                         float* __restrict__ out)
{
    __shared__ int part[4][64];
    int c = threadIdx.x & 63, rg = threadIdx.x >> 6;
    int j = blockIdx.x * 64 + c;
    int acc = 0;
    for (int b = rg; b < B_SZ; b += 4)
        acc += (int)(Xn[(size_t)b * NH + j] != 0) - (int)(Xp[(size_t)b * NH + j] != 0);
    part[rg][c] = acc;
    __syncthreads();
    if (rg == 0)
        out[j] = (float)(part[0][c] + part[1][c] + part[2][c] + part[3][c]) * (1.0f / 1024.0f);
}

__global__ void zero_kernel(unsigned* p) { *p = 0u; }

__global__ void loss_count2(const float* __restrict__ vdata,
                            const short* __restrict__ vneg, unsigned* cnt)
{
    __shared__ int part[4];
    int t = blockIdx.x * 256 + threadIdx.x;
    int local = 0;
#pragma unroll
    for (int it = 0; it < 8; ++it) {
        int e = t + it * 262144;
        int b = e >> 11, s = e & 2047;
        float st = vdata[(size_t)b * NV + 2 * s + 1];
        float sp = (vneg[(size_t)b * NV + 2 * s + 1] != 0) ? 1.0f : 0.0f;
        local += (st != sp) ? 1 : 0;
    }
#pragma unroll
    for (int off = 32; off; off >>= 1) local += __shfl_down(local, off, 64);
    if ((threadIdx.x & 63) == 0) part[threadIdx.x >> 6] = local;
    __syncthreads();
    if (threadIdx.x == 0)
        atomicAdd(cnt, (unsigned)(part[0] + part[1] + part[2] + part[3]));
}

__global__ void loss_final_kernel(const unsigned* cnt, float* out, float lp, float lm)
{
    float mis = (float)(*cnt);
    float mat = 2097152.0f - mis;
    out[0] = -((mat * lp + mis * lm) * (1.0f / 2097152.0f));
}

// ---------------- host ----------------
extern "C" void kernel_launch(void* const* d_in, const int* in_sizes, int n_in,
                              void* d_out, int out_size, void* d_ws, size_t ws_size,
                              hipStream_t stream)
{
    (void)in_sizes; (void)n_in; (void)out_size; (void)ws_size;
    const float* v_data = (const float*)d_in[0];
    const float* occ    = (const float*)d_in[1];
    const float* W1     = (const float*)d_in[2];
    const float* b_v    = (const float*)d_in[3];
    const float* b_h1   = (const float*)d_in[4];
    const float* W2     = (const float*)d_in[5];
    const float* b_h2   = (const float*)d_in[6];
    float* out = (float*)d_out;

    char* w = (char*)d_ws;
    short* vneg = (short*)w;                            // 5 x 8 MB fp16 states
    short* h1d  = vneg + (size_t)B_SZ * NV;
    short* h2d  = h1d  + (size_t)B_SZ * NH;
    short* h1c  = h2d  + (size_t)B_SZ * NH;
    short* h2n  = h1c  + (size_t)B_SZ * NH;
    float* P    = (float*)(h2n + (size_t)B_SZ * NH);    // 64 MB partials
    unsigned* cnt = (unsigned*)(P + (size_t)4 * 1024 * 4096);

    // d_out doubles as fp16 weight scratch (128 MB of the 134 MB output;
    // fully overwritten by gradient kernels afterwards).
    short* W1f = (short*)(((uintptr_t)(out + 1) + 15) & ~(uintptr_t)15);
    short* W1T = W1f + (size_t)NH * NV;
    short* W2f = W1T + (size_t)NH * NV;
    short* W2T = W2f + (size_t)NH * NH;

    // ---- JAX key derivation ----
    const uint32_t r0 = 0u, r1 = 42u;
    uint32_t kp1a, kp1b, kp2a, kp2b, kfa, kfb, kla, klb;
    tf2x32(r0, r1, 0u, 0u, kp1a, kp1b);
    tf2x32(r0, r1, 0u, 1u, kp2a, kp2b);
    tf2x32(r0, r1, 0u, 2u, kfa, kfb);
    tf2x32(r0, r1, 0u, 3u, kla, klb);
    uint32_t kaA[2], kaB[2], kbA[2], kbB[2], kcA[2], kcB[2];
    for (int i = 0; i < 2; ++i) {
        uint32_t fa, fb;
        tf2x32(kla, klb, 0u, (uint32_t)i, fa, fb);
        tf2x32(fa, fb, 0u, 0u, kaA[i], kaB[i]);
        tf2x32(fa, fb, 0u, 1u, kbA[i], kbB[i]);
        tf2x32(fa, fb, 0u, 2u, kcA[i], kcB[i]);
    }

    const int T = 256;
    const int NELEM = B_SZ * NH;
    dim3 gTr(64, 64);

    conv_tr<<<gTr, 256, 0, stream>>>(W1, W1f, W1T);
    conv_tr<<<gTr, 256, 0, stream>>>(W2, W2f, W2T);

    cvt_kernel<<<NELEM / T, T, 0, stream>>>(v_data, vneg, NELEM);

    // positive phase
    mm_chunk<0><<<512, 512, 0, stream>>>(vneg, nullptr, W1f, nullptr, P);
    combine_h<0, 4><<<2048, 256, 0, stream>>>(P, b_h1, h1d, nullptr, kp1a, kp1b);
    mm_chunk<0><<<512, 512, 0, stream>>>(h1d, nullptr, W2f, nullptr, P);
    combine_h<1, 4><<<2048, 256, 0, stream>>>(P, b_h2, h2d, h2n, kp2a, kp2b);

    // Gibbs loop (k = 2)
    for (int i = 0; i < 2; ++i) {
        mm_chunk<1><<<512, 512, 0, stream>>>(vneg, h2n, W1f, W2T, P);
        combine_h<0, 4><<<2048, 256, 0, stream>>>(P, b_h1, h1c, nullptr, kaA[i], kaB[i]);
        mm_chunk<2><<<512, 512, 0, stream>>>(h1c, nullptr, W2f, W1T, P);
        combine_dual<<<4096, 256, 0, stream>>>(P, b_h2, b_v, occ, h2n, vneg,
                                               kbA[i], kbB[i], kcA[i], kcB[i]);
    }

    // final hidden refresh
    mm_chunk<1><<<512, 512, 0, stream>>>(vneg, h2n, W1f, W2T, P);
    combine_h<0, 4><<<2048, 256, 0, stream>>>(P, b_h1, h1c, nullptr, kfa, kfb);

    // outputs (weight scratch dead after this point)
    float* dW1o  = out + 1;
    float* dbvo  = dW1o + (size_t)NH * NV;
    float* dbh1o = dbvo + NV;
    float* dW2o  = dbh1o + NH;
    float* dbh2o = dW2o + (size_t)NH * NH;

    grad_mm<1><<<dim3(NSGN / 128, NH / 128), T, 0, stream>>>(h1c, vneg, h1d, (short*)nullptr, v_data, dW1o);
    grad_mm<0><<<dim3(NH / 128, NH / 128), T, 0, stream>>>(h1c, h2n, h1d, h2d, (const float*)nullptr, dW2o);
    dbv_fast<<<NSGN / 64, T, 0, stream>>>(v_data, vneg, dbvo);
    dbh_fast<<<NH / 64, T, 0, stream>>>(h1d, h1c, dbh1o);
    dbh_fast<<<NH / 64, T, 0, stream>>>(h2d, h2n, dbh2o);

    zero_kernel<<<1, 1, 0, stream>>>(cnt);
    loss_count2<<<1024, T, 0, stream>>>(v_data, vneg, cnt);
    loss_final_kernel<<<1, 1, 0, stream>>>(cnt, out, logf(1.0f + 1e-7f), logf(1e-7f));
}

// Round 16
// 1226.274 us; speedup vs baseline: 1.1831x; 1.0296x over previous
//
#include <hip/hip_runtime.h>
#include <stdint.h>
#include <math.h>

#define B_SZ 1024
#define NV   4096
#define NH   4096
#define NSGN 2048

typedef short bf16x8 __attribute__((ext_vector_type(8)));
typedef short bf16x4 __attribute__((ext_vector_type(4)));
typedef float f32x4  __attribute__((ext_vector_type(4)));
typedef _Float16 f16x8 __attribute__((ext_vector_type(8)));

#define F16_ONE  ((short)0x3C00)
#define F16_NEG1 ((short)0xBC00)

// ---------------- threefry2x32 (JAX-compatible, 20 rounds) ----------------
__host__ __device__ __forceinline__ void tf2x32(uint32_t k0, uint32_t k1,
                                                uint32_t x0, uint32_t x1,
                                                uint32_t& o0, uint32_t& o1)
{
    uint32_t k2 = k0 ^ k1 ^ 0x1BD11BDAu;
#define TFR(r) { x0 += x1; x1 = (x1 << (r)) | (x1 >> (32 - (r))); x1 ^= x0; }
    x0 += k0; x1 += k1;
    TFR(13) TFR(15) TFR(26) TFR(6)
    x0 += k1; x1 += k2 + 1u;
    TFR(17) TFR(29) TFR(16) TFR(24)
    x0 += k2; x1 += k0 + 2u;
    TFR(13) TFR(15) TFR(26) TFR(6)
    x0 += k0; x1 += k1 + 3u;
    TFR(17) TFR(29) TFR(16) TFR(24)
    x0 += k1; x1 += k2 + 4u;
    TFR(13) TFR(15) TFR(26) TFR(6)
    x0 += k2; x1 += k0 + 5u;
#undef TFR
    o0 = x0; o1 = x1;
}

__device__ __forceinline__ float tf_uniform01(uint32_t k0, uint32_t k1, uint32_t idx)
{
    uint32_t a, b;
    tf2x32(k0, k1, 0u, idx, a, b);
    uint32_t bits = a ^ b;
    uint32_t fb = (bits >> 9) | 0x3F800000u;
    return __uint_as_float(fb) - 1.0f;
}

__device__ __forceinline__ float sigmoidf_(float x)
{
    if (x >= 0.0f) { float e = expf(-x); return 1.0f / (1.0f + e); }
    float e = expf(x); return e / (1.0f + e);
}

__device__ __forceinline__ void gl16(const void* g, void* l)
{
    __builtin_amdgcn_global_load_lds((const __attribute__((address_space(1))) void*)g,
                                     (__attribute__((address_space(3))) void*)l, 16, 0, 0);
}

// ---------------- weight precompute: fp32 -> fp16 direct + transposed ----------------
__global__ __launch_bounds__(256) void conv_tr(const float* __restrict__ W,
                                               short* __restrict__ Wf,
                                               short* __restrict__ Wt)
{
    __shared__ short t[64][65];
    const int bx = blockIdx.x * 64;
    const int by = blockIdx.y * 64;
    const int r0 = threadIdx.x >> 4;
    const int c0 = (threadIdx.x & 15) * 4;
#pragma unroll
    for (int i = 0; i < 4; ++i) {
        int row = by + r0 + i * 16;
        f32x4 v = *(const f32x4*)(W + (size_t)row * 4096 + bx + c0);
        short h[4];
#pragma unroll
        for (int j = 0; j < 4; ++j) {
            union { _Float16 f; short s; } u;
            u.f = (_Float16)v[j];
            h[j] = u.s;
        }
        *(bf16x4*)(Wf + (size_t)row * 4096 + bx + c0) = *(bf16x4*)h;
#pragma unroll
        for (int j = 0; j < 4; ++j) t[c0 + j][r0 + i * 16] = h[j];
    }
    __syncthreads();
#pragma unroll
    for (int i = 0; i < 4; ++i) {
        int orow = r0 + i * 16;
        short o[4] = { t[orow][c0], t[orow][c0 + 1], t[orow][c0 + 2], t[orow][c0 + 3] };
        *(bf16x4*)(Wt + (size_t)(bx + orow) * 4096 + by + c0) = *(bf16x4*)o;
    }
}

// ---------------- state transposes (for gradient bt-GEMMs) ----------------
// fp16 [1024][4096] -> [4096][1024], optional sign-negate
template<int NEG>
__global__ __launch_bounds__(256) void tr16(const short* __restrict__ in,
                                            short* __restrict__ out)
{
    __shared__ short t[64][65];
    const int bx = blockIdx.x * 64;   // col of in
    const int by = blockIdx.y * 64;   // row of in
    const int r0 = threadIdx.x >> 4;
    const int c0 = (threadIdx.x & 15) * 4;
#pragma unroll
    for (int i = 0; i < 4; ++i) {
        int row = by + r0 + i * 16;
        bf16x4 v = *(const bf16x4*)(in + (size_t)row * 4096 + bx + c0);
#pragma unroll
        for (int j = 0; j < 4; ++j)
            t[c0 + j][r0 + i * 16] = NEG ? (short)(v[j] ^ (short)0x8000) : v[j];
    }
    __syncthreads();
#pragma unroll
    for (int i = 0; i < 4; ++i) {
        int orow = r0 + i * 16;
        short o[4] = { t[orow][c0], t[orow][c0 + 1], t[orow][c0 + 2], t[orow][c0 + 3] };
        *(bf16x4*)(out + (size_t)(bx + orow) * 1024 + by + c0) = *(bf16x4*)o;
    }
}

// vneg fp16 [1024][4096] odd cols -> [2048][1024]
__global__ __launch_bounds__(256) void tr_sign(const short* __restrict__ in,
                                               short* __restrict__ out)
{
    __shared__ short t[64][65];
    const int bx = blockIdx.x * 64;   // s-range
    const int by = blockIdx.y * 64;   // b-range
    const int r0 = threadIdx.x >> 4;
    const int c0 = (threadIdx.x & 15) * 4;
#pragma unroll
    for (int i = 0; i < 4; ++i) {
        int row = by + r0 + i * 16;
        bf16x8 v = *(const bf16x8*)(in + (size_t)row * 4096 + 2 * (bx + c0));
#pragma unroll
        for (int j = 0; j < 4; ++j) t[c0 + j][r0 + i * 16] = v[2 * j + 1];
    }
    __syncthreads();
#pragma unroll
    for (int i = 0; i < 4; ++i) {
        int orow = r0 + i * 16;
        short o[4] = { t[orow][c0], t[orow][c0 + 1], t[orow][c0 + 2], t[orow][c0 + 3] };
        *(bf16x4*)(out + (size_t)(bx + orow) * 1024 + by + c0) = *(bf16x4*)o;
    }
}

// v_data f32 [1024][4096] odd cols -> fp16 [2048][1024], NEGATED (0/-1)
__global__ __launch_bounds__(256) void tr_signf(const float* __restrict__ in,
                                                short* __restrict__ out)
{
    __shared__ short t[64][65];
    const int bx = blockIdx.x * 64;
    const int by = blockIdx.y * 64;
    const int r0 = threadIdx.x >> 4;
    const int c0 = (threadIdx.x & 15) * 4;
#pragma unroll
    for (int i = 0; i < 4; ++i) {
        int row = by + r0 + i * 16;
        const float* p = in + (size_t)row * 4096 + 2 * (bx + c0);
        f32x4 a = *(const f32x4*)p;
        f32x4 b = *(const f32x4*)(p + 4);
        t[c0 + 0][r0 + i * 16] = (a[1] != 0.0f) ? F16_NEG1 : (short)0;
        t[c0 + 1][r0 + i * 16] = (a[3] != 0.0f) ? F16_NEG1 : (short)0;
        t[c0 + 2][r0 + i * 16] = (b[1] != 0.0f) ? F16_NEG1 : (short)0;
        t[c0 + 3][r0 + i * 16] = (b[3] != 0.0f) ? F16_NEG1 : (short)0;
    }
    __syncthreads();
#pragma unroll
    for (int i = 0; i < 4; ++i) {
        int orow = r0 + i * 16;
        short o[4] = { t[orow][c0], t[orow][c0 + 1], t[orow][c0 + 2], t[orow][c0 + 3] };
        *(bf16x4*)(out + (size_t)(bx + orow) * 1024 + by + c0) = *(bf16x4*)o;
    }
}

// =====================================================================
// Chunk GEMM, 256(M) x 128(N) tile, BK=32, 512 thr = 8 waves (4M x 2N),
// 48 KB LDS dbuf, 3 gl16/wave/step. Writes f32 partials P[ck][1024][NW].
// All grids 512 = 2 blocks/CU.
// =====================================================================
template<int MODE>
__global__ __launch_bounds__(512, 2) void mm_chunk(
    const short* __restrict__ A0, const short* __restrict__ A1,
    const short* __restrict__ B0, const short* __restrict__ B1,
    float* __restrict__ P)
{
    __shared__ __align__(1024) short As[2][16 * 512];
    __shared__ __align__(1024) short Bs[2][8 * 512];

    const int bid = blockIdx.x;
    const int xcd = bid & 7, slot = bid >> 3;

    int bm, bncol, ck, kbase, NW;
    const short* Ap;
    const short* Bp;
    if (MODE == 2) {
        int pn = xcd * 8 + (slot & 7);          // 0..63
        bm = ((slot >> 3) & 3) * 256;
        ck = slot >> 5;                         // 0..1
        kbase = ck * 2048;
        Ap = A0;
        Bp = (pn < 32) ? (B0 + (size_t)pn * 128 * 4096)
                       : (B1 + (size_t)(pn - 32) * 128 * 4096);
        bncol = pn * 128;
        NW = 8192;
    } else {
        int pn = xcd * 4 + (slot & 3);          // 0..31
        bm = ((slot >> 2) & 3) * 256;
        ck = slot >> 4;                         // 0..3
        if (MODE == 1) {
            if (ck >= 2) { Ap = A1; Bp = B1 + (size_t)pn * 128 * 4096; kbase = (ck - 2) * 2048; }
            else         { Ap = A0; Bp = B0 + (size_t)pn * 128 * 4096; kbase = ck * 2048; }
        } else {
            Ap = A0; Bp = B0 + (size_t)pn * 128 * 4096; kbase = ck * 1024;
        }
        bncol = pn * 128;
        NW = 4096;
    }

    const int NT = (MODE == 0) ? 32 : 64;

    const int tid = threadIdx.x;
    const int wv = tid >> 6, lane = tid & 63;
    const int l15 = lane & 15, l4 = lane >> 4;
    const int fr = l15, fc = l4 * 8;
    const int wm = wv >> 1, wn = wv & 1;

    f32x4 acc[4][4] = {};

    auto stage = [&](int buf, int t) {
        const int kk = kbase + t * 32;
        gl16(Ap + (size_t)(bm + (wv * 2 + 0) * 16 + fr) * 4096 + kk + fc, &As[buf][(wv * 2 + 0) * 512]);
        gl16(Ap + (size_t)(bm + (wv * 2 + 1) * 16 + fr) * 4096 + kk + fc, &As[buf][(wv * 2 + 1) * 512]);
        gl16(Bp + (size_t)(wv * 16 + fr) * 4096 + kk + fc, &Bs[buf][wv * 512]);
    };
    auto compute = [&](int buf) {
        f16x8 xf[4], yf[4];
#pragma unroll
        for (int m = 0; m < 4; ++m)
            xf[m] = *(f16x8*)&As[buf][(wm * 4 + m) * 512 + lane * 8];
#pragma unroll
        for (int n = 0; n < 4; ++n)
            yf[n] = *(f16x8*)&Bs[buf][(wn * 4 + n) * 512 + lane * 8];
#pragma unroll
        for (int m = 0; m < 4; ++m)
#pragma unroll
            for (int n = 0; n < 4; ++n)
                acc[m][n] = __builtin_amdgcn_mfma_f32_16x16x32_f16(xf[m], yf[n], acc[m][n], 0, 0, 0);
    };

    stage(0, 0);
    __syncthreads();
    for (int t = 0; t < NT; ++t) {
        const int cur = t & 1;
        if (t + 1 < NT) stage(cur ^ 1, t + 1);
        compute(cur);
        __syncthreads();
    }

    float* Pc = P + (size_t)ck * 1024 * NW;
#pragma unroll
    for (int m = 0; m < 4; ++m)
#pragma unroll
        for (int n = 0; n < 4; ++n)
#pragma unroll
            for (int r = 0; r < 4; ++r) {
                int row = bm + wm * 64 + m * 16 + l4 * 4 + r;
                int col = bncol + wn * 64 + n * 16 + l15;
                Pc[(size_t)row * NW + col] = acc[m][n][r];
            }
}

// =====================================================================
// Gradient bt-GEMMs on TRANSPOSED operands (pos-Y pre-negated).
// Exact integer sums / 1024 -> bit-identical to previous grad path.
// =====================================================================
// dW2: 256x128 tile, 512 thr, grid 512; K-concat 2048 (neg 1024, pos 1024)
__global__ __launch_bounds__(512, 2) void grad2(
    const short* __restrict__ XnT, const short* __restrict__ YnT,
    const short* __restrict__ XpT, const short* __restrict__ YpT,
    float* __restrict__ Out)
{
    __shared__ __align__(1024) short As[2][16 * 512];
    __shared__ __align__(1024) short Bs[2][8 * 512];

    const int bid = blockIdx.x;
    const int xcd = bid & 7, slot = bid >> 3;   // 0..63
    const int pn = xcd * 4 + (slot & 3);        // 0..31
    const int bm = (slot >> 2) * 256;           // 16 tiles

    const int tid = threadIdx.x;
    const int wv = tid >> 6, lane = tid & 63;
    const int l15 = lane & 15, l4 = lane >> 4;
    const int fr = l15, fc = l4 * 8;
    const int wm = wv >> 1, wn = wv & 1;

    f32x4 acc[4][4] = {};

    auto stage = [&](int buf, int t) {
        const short* X = (t < 32) ? XnT : XpT;
        const short* Y = (t < 32) ? YnT : YpT;
        const int kk = (t & 31) * 32;
        gl16(X + (size_t)(bm + (wv * 2 + 0) * 16 + fr) * 1024 + kk + fc, &As[buf][(wv * 2 + 0) * 512]);
        gl16(X + (size_t)(bm + (wv * 2 + 1) * 16 + fr) * 1024 + kk + fc, &As[buf][(wv * 2 + 1) * 512]);
        gl16(Y + (size_t)(pn * 128 + wv * 16 + fr) * 1024 + kk + fc, &Bs[buf][wv * 512]);
    };
    auto compute = [&](int buf) {
        f16x8 xf[4], yf[4];
#pragma unroll
        for (int m = 0; m < 4; ++m)
            xf[m] = *(f16x8*)&As[buf][(wm * 4 + m) * 512 + lane * 8];
#pragma unroll
        for (int n = 0; n < 4; ++n)
            yf[n] = *(f16x8*)&Bs[buf][(wn * 4 + n) * 512 + lane * 8];
#pragma unroll
        for (int m = 0; m < 4; ++m)
#pragma unroll
            for (int n = 0; n < 4; ++n)
                acc[m][n] = __builtin_amdgcn_mfma_f32_16x16x32_f16(xf[m], yf[n], acc[m][n], 0, 0, 0);
    };

    stage(0, 0);
    __syncthreads();
    for (int t = 0; t < 64; ++t) {
        const int cur = t & 1;
        if (t + 1 < 64) stage(cur ^ 1, t + 1);
        compute(cur);
        __syncthreads();
    }

    const float invB = 1.0f / 1024.0f;
#pragma unroll
    for (int m = 0; m < 4; ++m)
#pragma unroll
        for (int n = 0; n < 4; ++n)
#pragma unroll
            for (int r = 0; r < 4; ++r) {
                int i_ = bm + wm * 64 + m * 16 + l4 * 4 + r;
                int j_ = pn * 128 + wn * 64 + n * 16 + l15;
                Out[(size_t)i_ * 4096 + j_] = acc[m][n][r] * invB;
            }
}

// dW1: 128x128 tile, 256 thr = 4 waves (64x64), grid 512; N=2048 (sign cols)
__global__ __launch_bounds__(256, 4) void grad1(
    const short* __restrict__ XnT, const short* __restrict__ YnT,
    const short* __restrict__ XpT, const short* __restrict__ YpT,
    float* __restrict__ Out)
{
    __shared__ __align__(1024) short As[2][8 * 512];
    __shared__ __align__(1024) short Bs[2][8 * 512];

    const int bid = blockIdx.x;
    const int xcd = bid & 7, slot = bid >> 3;   // 0..63
    const int pn = xcd * 2 + (slot & 1);        // 0..15
    const int bm = (slot >> 1) * 128;           // 32 tiles

    const int tid = threadIdx.x;
    const int wv = tid >> 6, lane = tid & 63;
    const int l15 = lane & 15, l4 = lane >> 4;
    const int fr = l15, fc = l4 * 8;
    const int wm = wv >> 1, wn = wv & 1;

    f32x4 acc[4][4] = {};

    auto stage = [&](int buf, int t) {
        const short* X = (t < 32) ? XnT : XpT;
        const short* Y = (t < 32) ? YnT : YpT;
        const int kk = (t & 31) * 32;
#pragma unroll
        for (int c = 0; c < 2; ++c) {
            int sub = wv * 2 + c;
            gl16(X + (size_t)(bm + sub * 16 + fr) * 1024 + kk + fc, &As[buf][sub * 512]);
            gl16(Y + (size_t)(pn * 128 + sub * 16 + fr) * 1024 + kk + fc, &Bs[buf][sub * 512]);
        }
    };
    auto compute = [&](int buf) {
        f16x8 xf[4], yf[4];
#pragma unroll
        for (int m = 0; m < 4; ++m)
            xf[m] = *(f16x8*)&As[buf][(wm * 4 + m) * 512 + lane * 8];
#pragma unroll
        for (int n = 0; n < 4; ++n)
            yf[n] = *(f16x8*)&Bs[buf][(wn * 4 + n) * 512 + lane * 8];
#pragma unroll
        for (int m = 0; m < 4; ++m)
#pragma unroll
            for (int n = 0; n < 4; ++n)
                acc[m][n] = __builtin_amdgcn_mfma_f32_16x16x32_f16(xf[m], yf[n], acc[m][n], 0, 0, 0);
    };

    stage(0, 0);
    __syncthreads();
    for (int t = 0; t < 64; ++t) {
        const int cur = t & 1;
        if (t + 1 < 64) stage(cur ^ 1, t + 1);
        compute(cur);
        __syncthreads();
    }

    const float invB = 1.0f / 1024.0f;
#pragma unroll
    for (int m = 0; m < 4; ++m)
#pragma unroll
        for (int n = 0; n < 4; ++n)
#pragma unroll
            for (int r = 0; r < 4; ++r) {
                int i_ = bm + wm * 64 + m * 16 + l4 * 4 + r;
                int j_ = pn * 128 + wn * 64 + n * 16 + l15;
                Out[(size_t)i_ * 4096 + 2 * j_ + 1] = acc[m][n][r] * invB;
                Out[(size_t)i_ * 4096 + 2 * j_]     = 0.0f;
            }
}

// ---------------- combine + sample (N=4096 logits) ----------------
template<int EPI, int NC>
__global__ __launch_bounds__(256) void combine_h(
    const float* __restrict__ P, const float* __restrict__ bias,
    short* __restrict__ O0, short* __restrict__ O1,
    uint32_t k0, uint32_t k1)
{
    size_t e0 = ((size_t)blockIdx.x * 256 + threadIdx.x) * 8;
    f32x4 s0 = {}, s1 = {};
#pragma unroll
    for (int c = 0; c < NC; ++c) {
        const float* p = P + (size_t)c * 4194304 + e0;
        s0 += *(const f32x4*)p;
        s1 += *(const f32x4*)(p + 4);
    }
    int col = (int)(e0 & 4095);
    short o[8];
#pragma unroll
    for (int j = 0; j < 8; ++j) {
        float v = ((j < 4) ? s0[j] : s1[j - 4]) + bias[col + j];
        float pr = sigmoidf_(v);
        float u = tf_uniform01(k0, k1, (uint32_t)(e0 + j));
        o[j] = (u < pr) ? F16_ONE : (short)0;
    }
    *(bf16x8*)&O0[e0] = *(bf16x8*)o;
    if (EPI == 1) *(bf16x8*)&O1[e0] = *(bf16x8*)o;
}

// ---------------- combine + sample (dual N=8192: h2 | pv-sign) ----------------
__global__ __launch_bounds__(256) void combine_dual(
    const float* __restrict__ P,
    const float* __restrict__ b_h2, const float* __restrict__ b_v,
    const float* __restrict__ occ,
    short* __restrict__ h2n, short* __restrict__ vneg,
    uint32_t kb0, uint32_t kb1, uint32_t kc0, uint32_t kc1)
{
    size_t e0 = ((size_t)blockIdx.x * 256 + threadIdx.x) * 8;
    int row = (int)(e0 >> 13);
    int cl  = (int)(e0 & 8191);
    f32x4 s0 = {}, s1 = {};
#pragma unroll
    for (int c = 0; c < 2; ++c) {
        const float* p = P + (size_t)c * 8388608 + e0;
        s0 += *(const f32x4*)p;
        s1 += *(const f32x4*)(p + 4);
    }
    short o[8];
    if (cl < 4096) {
#pragma unroll
        for (int j = 0; j < 8; ++j) {
            float v = ((j < 4) ? s0[j] : s1[j - 4]) + b_h2[cl + j];
            float pr = sigmoidf_(v);
            size_t e = (size_t)row * 4096 + cl + j;
            float u = tf_uniform01(kb0, kb1, (uint32_t)e);
            o[j] = (u < pr) ? F16_ONE : (short)0;
        }
        *(bf16x8*)&h2n[(size_t)row * 4096 + cl] = *(bf16x8*)o;
    } else {
        int v0 = cl - 4096;
#pragma unroll
        for (int j = 0; j < 8; ++j) {
            int vcol = v0 + j;
            if (vcol & 1) {
                int s = (vcol - 1) >> 1;
                float v = ((j < 4) ? s0[j] : s1[j - 4]) + b_v[vcol];
                float pr = sigmoidf_(v);
                float u = tf_uniform01(kc0, kc1, (uint32_t)(row * 2048 + s));
                o[j] = (u < pr) ? F16_ONE : (short)0;
            } else {
                o[j] = (occ[(size_t)row * 2048 + (vcol >> 1)] != 0.0f) ? F16_ONE : (short)0;
            }
        }
        *(bf16x8*)&vneg[(size_t)row * 4096 + v0] = *(bf16x8*)o;
    }
}

// ---------------- small kernels ----------------
__global__ void cvt_kernel(const float* __restrict__ in, short* __restrict__ out, int n)
{
    int e = blockIdx.x * 256 + threadIdx.x;
    if (e < n) out[e] = (in[e] != 0.0f) ? F16_ONE : (short)0;
}

__global__ void dbv_fast(const float* __restrict__ vdata, const short* __restrict__ vneg,
                         float* __restrict__ out)
{
    __shared__ float part[4][64];
    int c = threadIdx.x & 63, rg = threadIdx.x >> 6;
    int s = blockIdx.x * 64 + c;
    float acc = 0.0f;
    for (int b = rg; b < B_SZ; b += 4)
        acc += ((vneg[(size_t)b * NV + 2 * s + 1] != 0) ? 1.0f : 0.0f)
             - vdata[(size_t)b * NV + 2 * s + 1];
    part[rg][c] = acc;
    __syncthreads();
    if (rg == 0) {
        out[2 * s + 1] = (part[0][c] + part[1][c] + part[2][c] + part[3][c]) * (1.0f / 1024.0f);
        out[2 * s] = 0.0f;
    }
}

__global__ void dbh_fast(const short* __restrict__ Xp, const short* __restrict__ Xn,
                         float* __restrict__ out)
{
    __shared__ int part[4][64];
    int c = threadIdx.x & 63, rg = threadIdx.x >> 6;
    int j = blockIdx.x * 64 + c;
    int acc = 0;
    for (int b = rg; b < B_SZ; b += 4)
        acc += (int)(Xn[(size_t)b * NH + j] != 0) - (int)(Xp[(size_t)b * NH + j] != 0);
    part[rg][c] = acc;
    __syncthreads();
    if (rg == 0)
        out[j] = (float)(part[0][c] + part[1][c] + part[2][c] + part[3][c]) * (1.0f / 1024.0f);
}

__global__ void zero_kernel(unsigned* p) { *p = 0u; }

__global__ void loss_count2(const float* __restrict__ vdata,
                            const short* __restrict__ vneg, unsigned* cnt)
{
    __shared__ int part[4];
    int t = blockIdx.x * 256 + threadIdx.x;
    int local = 0;
#pragma unroll
    for (int it = 0; it < 8; ++it) {
        int e = t + it * 262144;
        int b = e >> 11, s = e & 2047;
        float st = vdata[(size_t)b * NV + 2 * s + 1];
        float sp = (vneg[(size_t)b * NV + 2 * s + 1] != 0) ? 1.0f : 0.0f;
        local += (st != sp) ? 1 : 0;
    }
#pragma unroll
    for (int off = 32; off; off >>= 1) local += __shfl_down(local, off, 64);
    if ((threadIdx.x & 63) == 0) part[threadIdx.x >> 6] = local;
    __syncthreads();
    if (threadIdx.x == 0)
        atomicAdd(cnt, (unsigned)(part[0] + part[1] + part[2] + part[3]));
}

__global__ void loss_final_kernel(const unsigned* cnt, float* out, float lp, float lm)
{
    float mis = (float)(*cnt);
    float mat = 2097152.0f - mis;
    out[0] = -((mat * lp + mis * lm) * (1.0f / 2097152.0f));
}

// ---------------- host ----------------
extern "C" void kernel_launch(void* const* d_in, const int* in_sizes, int n_in,
                              void* d_out, int out_size, void* d_ws, size_t ws_size,
                              hipStream_t stream)
{
    (void)in_sizes; (void)n_in; (void)out_size; (void)ws_size;
    const float* v_data = (const float*)d_in[0];
    const float* occ    = (const float*)d_in[1];
    const float* W1     = (const float*)d_in[2];
    const float* b_v    = (const float*)d_in[3];
    const float* b_h1   = (const float*)d_in[4];
    const float* W2     = (const float*)d_in[5];
    const float* b_h2   = (const float*)d_in[6];
    float* out = (float*)d_out;

    char* w = (char*)d_ws;
    short* vneg = (short*)w;                            // 5 x 8 MB fp16 states
    short* h1d  = vneg + (size_t)B_SZ * NV;
    short* h2d  = h1d  + (size_t)B_SZ * NH;
    short* h1c  = h2d  + (size_t)B_SZ * NH;
    short* h2n  = h1c  + (size_t)B_SZ * NH;
    float* P    = (float*)(h2n + (size_t)B_SZ * NH);    // 64 MB partials
    unsigned* cnt = (unsigned*)(P + (size_t)4 * 1024 * 4096);

    // Transposed gradient operands alias P (P is dead after the last combine).
    short* h1cT  = (short*)P;                           // [4096][1024]
    short* h1dT  = h1cT  + (size_t)4096 * 1024;
    short* h2nT  = h1dT  + (size_t)4096 * 1024;
    short* h2dTn = h2nT  + (size_t)4096 * 1024;         // negated
    short* vsT   = h2dTn + (size_t)4096 * 1024;         // [2048][1024]
    short* vdsTn = vsT   + (size_t)2048 * 1024;         // negated

    // d_out doubles as fp16 weight scratch (overwritten by gradients later).
    short* W1f = (short*)(((uintptr_t)(out + 1) + 15) & ~(uintptr_t)15);
    short* W1T = W1f + (size_t)NH * NV;
    short* W2f = W1T + (size_t)NH * NV;
    short* W2T = W2f + (size_t)NH * NH;

    // ---- JAX key derivation ----
    const uint32_t r0 = 0u, r1 = 42u;
    uint32_t kp1a, kp1b, kp2a, kp2b, kfa, kfb, kla, klb;
    tf2x32(r0, r1, 0u, 0u, kp1a, kp1b);
    tf2x32(r0, r1, 0u, 1u, kp2a, kp2b);
    tf2x32(r0, r1, 0u, 2u, kfa, kfb);
    tf2x32(r0, r1, 0u, 3u, kla, klb);
    uint32_t kaA[2], kaB[2], kbA[2], kbB[2], kcA[2], kcB[2];
    for (int i = 0; i < 2; ++i) {
        uint32_t fa, fb;
        tf2x32(kla, klb, 0u, (uint32_t)i, fa, fb);
        tf2x32(fa, fb, 0u, 0u, kaA[i], kaB[i]);
        tf2x32(fa, fb, 0u, 1u, kbA[i], kbB[i]);
        tf2x32(fa, fb, 0u, 2u, kcA[i], kcB[i]);
    }

    const int T = 256;
    const int NELEM = B_SZ * NH;
    dim3 gTr(64, 64);

    conv_tr<<<gTr, 256, 0, stream>>>(W1, W1f, W1T);
    conv_tr<<<gTr, 256, 0, stream>>>(W2, W2f, W2T);

    cvt_kernel<<<NELEM / T, T, 0, stream>>>(v_data, vneg, NELEM);

    // positive phase
    mm_chunk<0><<<512, 512, 0, stream>>>(vneg, nullptr, W1f, nullptr, P);
    combine_h<0, 4><<<2048, 256, 0, stream>>>(P, b_h1, h1d, nullptr, kp1a, kp1b);
    mm_chunk<0><<<512, 512, 0, stream>>>(h1d, nullptr, W2f, nullptr, P);
    combine_h<1, 4><<<2048, 256, 0, stream>>>(P, b_h2, h2d, h2n, kp2a, kp2b);

    // Gibbs loop (k = 2)
    for (int i = 0; i < 2; ++i) {
        mm_chunk<1><<<512, 512, 0, stream>>>(vneg, h2n, W1f, W2T, P);
        combine_h<0, 4><<<2048, 256, 0, stream>>>(P, b_h1, h1c, nullptr, kaA[i], kaB[i]);
        mm_chunk<2><<<512, 512, 0, stream>>>(h1c, nullptr, W2f, W1T, P);
        combine_dual<<<4096, 256, 0, stream>>>(P, b_h2, b_v, occ, h2n, vneg,
                                               kbA[i], kbB[i], kcA[i], kcB[i]);
    }

    // final hidden refresh
    mm_chunk<1><<<512, 512, 0, stream>>>(vneg, h2n, W1f, W2T, P);
    combine_h<0, 4><<<2048, 256, 0, stream>>>(P, b_h1, h1c, nullptr, kfa, kfb);

    // ---- gradients (transposed bt path; P now dead, reused) ----
    float* dW1o  = out + 1;
    float* dbvo  = dW1o + (size_t)NH * NV;
    float* dbh1o = dbvo + NV;
    float* dW2o  = dbh1o + NH;
    float* dbh2o = dW2o + (size_t)NH * NH;

    dim3 gT16(64, 16), gTS(32, 16);
    tr16<0><<<gT16, 256, 0, stream>>>(h1c, h1cT);
    tr16<0><<<gT16, 256, 0, stream>>>(h1d, h1dT);
    tr16<0><<<gT16, 256, 0, stream>>>(h2n, h2nT);
    tr16<1><<<gT16, 256, 0, stream>>>(h2d, h2dTn);
    tr_sign<<<gTS, 256, 0, stream>>>(vneg, vsT);
    tr_signf<<<gTS, 256, 0, stream>>>(v_data, vdsTn);

    grad1<<<512, 256, 0, stream>>>(h1cT, vsT, h1dT, vdsTn, dW1o);
    grad2<<<512, 512, 0, stream>>>(h1cT, h2nT, h1dT, h2dTn, dW2o);

    dbv_fast<<<NSGN / 64, T, 0, stream>>>(v_data, vneg, dbvo);
    dbh_fast<<<NH / 64, T, 0, stream>>>(h1d, h1c, dbh1o);
    dbh_fast<<<NH / 64, T, 0, stream>>>(h2d, h2n, dbh2o);

    zero_kernel<<<1, 1, 0, stream>>>(cnt);
    loss_count2<<<1024, T, 0, stream>>>(v_data, vneg, cnt);
    loss_final_kernel<<<1, 1, 0, stream>>>(cnt, out, logf(1.0f + 1e-7f), logf(1e-7f));
}

// Round 17
// 1183.411 us; speedup vs baseline: 1.2260x; 1.0362x over previous
//
#include <hip/hip_runtime.h>
#include <stdint.h>
#include <math.h>

#define B_SZ 1024
#define NV   4096
#define NH   4096
#define NSGN 2048

typedef short bf16x8 __attribute__((ext_vector_type(8)));
typedef short bf16x4 __attribute__((ext_vector_type(4)));
typedef float f32x4  __attribute__((ext_vector_type(4)));
typedef _Float16 f16x8 __attribute__((ext_vector_type(8)));

#define F16_ONE  ((short)0x3C00)
#define F16_NEG1 ((short)0xBC00)

__device__ __forceinline__ short f32_to_f16s(float f)
{
    union { _Float16 h; short s; } u;
    u.h = (_Float16)f;
    return u.s;
}

// ---------------- threefry2x32 (JAX-compatible, 20 rounds) ----------------
__host__ __device__ __forceinline__ void tf2x32(uint32_t k0, uint32_t k1,
                                                uint32_t x0, uint32_t x1,
                                                uint32_t& o0, uint32_t& o1)
{
    uint32_t k2 = k0 ^ k1 ^ 0x1BD11BDAu;
#define TFR(r) { x0 += x1; x1 = (x1 << (r)) | (x1 >> (32 - (r))); x1 ^= x0; }
    x0 += k0; x1 += k1;
    TFR(13) TFR(15) TFR(26) TFR(6)
    x0 += k1; x1 += k2 + 1u;
    TFR(17) TFR(29) TFR(16) TFR(24)
    x0 += k2; x1 += k0 + 2u;
    TFR(13) TFR(15) TFR(26) TFR(6)
    x0 += k0; x1 += k1 + 3u;
    TFR(17) TFR(29) TFR(16) TFR(24)
    x0 += k1; x1 += k2 + 4u;
    TFR(13) TFR(15) TFR(26) TFR(6)
    x0 += k2; x1 += k0 + 5u;
#undef TFR
    o0 = x0; o1 = x1;
}

__device__ __forceinline__ float tf_uniform01(uint32_t k0, uint32_t k1, uint32_t idx)
{
    uint32_t a, b;
    tf2x32(k0, k1, 0u, idx, a, b);
    uint32_t bits = a ^ b;
    uint32_t fb = (bits >> 9) | 0x3F800000u;
    return __uint_as_float(fb) - 1.0f;
}

__device__ __forceinline__ float sigmoidf_(float x)
{
    if (x >= 0.0f) { float e = expf(-x); return 1.0f / (1.0f + e); }
    float e = expf(x); return e / (1.0f + e);
}

__device__ __forceinline__ void gl16(const void* g, void* l)
{
    __builtin_amdgcn_global_load_lds((const __attribute__((address_space(1))) void*)g,
                                     (__attribute__((address_space(3))) void*)l, 16, 0, 0);
}

// ---------------- weight precompute ----------------
// W2: fp16 direct + full transpose
__global__ __launch_bounds__(256) void conv_tr(const float* __restrict__ W,
                                               short* __restrict__ Wf,
                                               short* __restrict__ Wt)
{
    __shared__ short t[64][65];
    const int bx = blockIdx.x * 64;
    const int by = blockIdx.y * 64;
    const int r0 = threadIdx.x >> 4;
    const int c0 = (threadIdx.x & 15) * 4;
#pragma unroll
    for (int i = 0; i < 4; ++i) {
        int row = by + r0 + i * 16;
        f32x4 v = *(const f32x4*)(W + (size_t)row * 4096 + bx + c0);
        short h[4];
#pragma unroll
        for (int j = 0; j < 4; ++j) h[j] = f32_to_f16s(v[j]);
        *(bf16x4*)(Wf + (size_t)row * 4096 + bx + c0) = *(bf16x4*)h;
#pragma unroll
        for (int j = 0; j < 4; ++j) t[c0 + j][r0 + i * 16] = h[j];
    }
    __syncthreads();
#pragma unroll
    for (int i = 0; i < 4; ++i) {
        int orow = r0 + i * 16;
        short o[4] = { t[orow][c0], t[orow][c0 + 1], t[orow][c0 + 2], t[orow][c0 + 3] };
        *(bf16x4*)(Wt + (size_t)(bx + orow) * 4096 + by + c0) = *(bf16x4*)o;
    }
}

// W1: fp16 direct (elementwise)
__global__ __launch_bounds__(256) void conv_f16(const float* __restrict__ W,
                                                short* __restrict__ Wf)
{
    size_t i = ((size_t)blockIdx.x * 256 + threadIdx.x) * 4;
    f32x4 v = *(const f32x4*)(W + i);
    short h[4];
#pragma unroll
    for (int c = 0; c < 4; ++c) h[c] = f32_to_f16s(v[c]);
    *(bf16x4*)(Wf + i) = *(bf16x4*)h;
}

// W1 odd cols -> fp16 transpose: W1To[j][k] = f16(W1[k][2j+1]), [2048][4096]
__global__ __launch_bounds__(256) void conv_trodd(const float* __restrict__ W,
                                                  short* __restrict__ Wt)
{
    __shared__ short t[64][65];
    const int bx = blockIdx.x * 64;   // j-range (0..2047)
    const int by = blockIdx.y * 64;   // k-range (0..4095)
    const int r0 = threadIdx.x >> 4;
    const int c0 = (threadIdx.x & 15) * 4;
#pragma unroll
    for (int i = 0; i < 4; ++i) {
        int row = by + r0 + i * 16;
        const float* p = W + (size_t)row * 4096 + 2 * (bx + c0);
        f32x4 a = *(const f32x4*)p;
        f32x4 b = *(const f32x4*)(p + 4);
        t[c0 + 0][r0 + i * 16] = f32_to_f16s(a[1]);
        t[c0 + 1][r0 + i * 16] = f32_to_f16s(a[3]);
        t[c0 + 2][r0 + i * 16] = f32_to_f16s(b[1]);
        t[c0 + 3][r0 + i * 16] = f32_to_f16s(b[3]);
    }
    __syncthreads();
#pragma unroll
    for (int i = 0; i < 4; ++i) {
        int orow = r0 + i * 16;
        short o[4] = { t[orow][c0], t[orow][c0 + 1], t[orow][c0 + 2], t[orow][c0 + 3] };
        *(bf16x4*)(Wt + (size_t)(bx + orow) * 4096 + by + c0) = *(bf16x4*)o;
    }
}

// ---------------- state transposes (for gradient bt-GEMMs) ----------------
template<int NEG>
__global__ __launch_bounds__(256) void tr16(const short* __restrict__ in,
                                            short* __restrict__ out)
{
    __shared__ short t[64][65];
    const int bx = blockIdx.x * 64;
    const int by = blockIdx.y * 64;
    const int r0 = threadIdx.x >> 4;
    const int c0 = (threadIdx.x & 15) * 4;
#pragma unroll
    for (int i = 0; i < 4; ++i) {
        int row = by + r0 + i * 16;
        bf16x4 v = *(const bf16x4*)(in + (size_t)row * 4096 + bx + c0);
#pragma unroll
        for (int j = 0; j < 4; ++j)
            t[c0 + j][r0 + i * 16] = NEG ? (short)(v[j] ^ (short)0x8000) : v[j];
    }
    __syncthreads();
#pragma unroll
    for (int i = 0; i < 4; ++i) {
        int orow = r0 + i * 16;
        short o[4] = { t[orow][c0], t[orow][c0 + 1], t[orow][c0 + 2], t[orow][c0 + 3] };
        *(bf16x4*)(out + (size_t)(bx + orow) * 1024 + by + c0) = *(bf16x4*)o;
    }
}

__global__ __launch_bounds__(256) void tr_sign(const short* __restrict__ in,
                                               short* __restrict__ out)
{
    __shared__ short t[64][65];
    const int bx = blockIdx.x * 64;
    const int by = blockIdx.y * 64;
    const int r0 = threadIdx.x >> 4;
    const int c0 = (threadIdx.x & 15) * 4;
#pragma unroll
    for (int i = 0; i < 4; ++i) {
        int row = by + r0 + i * 16;
        bf16x8 v = *(const bf16x8*)(in + (size_t)row * 4096 + 2 * (bx + c0));
#pragma unroll
        for (int j = 0; j < 4; ++j) t[c0 + j][r0 + i * 16] = v[2 * j + 1];
    }
    __syncthreads();
#pragma unroll
    for (int i = 0; i < 4; ++i) {
        int orow = r0 + i * 16;
        short o[4] = { t[orow][c0], t[orow][c0 + 1], t[orow][c0 + 2], t[orow][c0 + 3] };
        *(bf16x4*)(out + (size_t)(bx + orow) * 1024 + by + c0) = *(bf16x4*)o;
    }
}

__global__ __launch_bounds__(256) void tr_signf(const float* __restrict__ in,
                                                short* __restrict__ out)
{
    __shared__ short t[64][65];
    const int bx = blockIdx.x * 64;
    const int by = blockIdx.y * 64;
    const int r0 = threadIdx.x >> 4;
    const int c0 = (threadIdx.x & 15) * 4;
#pragma unroll
    for (int i = 0; i < 4; ++i) {
        int row = by + r0 + i * 16;
        const float* p = in + (size_t)row * 4096 + 2 * (bx + c0);
        f32x4 a = *(const f32x4*)p;
        f32x4 b = *(const f32x4*)(p + 4);
        t[c0 + 0][r0 + i * 16] = (a[1] != 0.0f) ? F16_NEG1 : (short)0;
        t[c0 + 1][r0 + i * 16] = (a[3] != 0.0f) ? F16_NEG1 : (short)0;
        t[c0 + 2][r0 + i * 16] = (b[1] != 0.0f) ? F16_NEG1 : (short)0;
        t[c0 + 3][r0 + i * 16] = (b[3] != 0.0f) ? F16_NEG1 : (short)0;
    }
    __syncthreads();
#pragma unroll
    for (int i = 0; i < 4; ++i) {
        int orow = r0 + i * 16;
        short o[4] = { t[orow][c0], t[orow][c0 + 1], t[orow][c0 + 2], t[orow][c0 + 3] };
        *(bf16x4*)(out + (size_t)(bx + orow) * 1024 + by + c0) = *(bf16x4*)o;
    }
}

// =====================================================================
// Chunk GEMM, 256(M) x 128(N) tile, BK=32, 512 thr = 8 waves (4M x 2N),
// 48 KB LDS dbuf, 3 gl16/wave/step. Writes FP16 partials P[ck][1024][NW].
//  MODE 0: K=4096 -> 4 chunks of 1024 (A0,B0), 32 steps. grid 512.
//  MODE 1: K=8192 concat -> 4 chunks of 2048, 64 steps. grid 512.
//  MODE 2: dual-N 6144 (48 panels: W2f pn<32, W1To pn>=32), K=4096 ->
//          2 chunks of 2048, 64 steps. grid 384.
// =====================================================================
template<int MODE>
__global__ __launch_bounds__(512, 2) void mm_chunk(
    const short* __restrict__ A0, const short* __restrict__ A1,
    const short* __restrict__ B0, const short* __restrict__ B1,
    short* __restrict__ P)
{
    __shared__ __align__(1024) short As[2][16 * 512];
    __shared__ __align__(1024) short Bs[2][8 * 512];

    const int bid = blockIdx.x;
    const int xcd = bid & 7, slot = bid >> 3;

    int bm, bncol, ck, kbase, NW;
    const short* Ap;
    const short* Bp;
    if (MODE == 2) {
        int slot6 = slot % 6, rest = slot / 6;  // slot 0..47
        int pn = xcd * 6 + slot6;               // 0..47
        bm = (rest & 3) * 256;
        ck = rest >> 2;                         // 0..1
        kbase = ck * 2048;
        Ap = A0;
        Bp = (pn < 32) ? (B0 + (size_t)pn * 128 * 4096)
                       : (B1 + (size_t)(pn - 32) * 128 * 4096);
        bncol = pn * 128;
        NW = 6144;
    } else {
        int pn = xcd * 4 + (slot & 3);          // 0..31
        bm = ((slot >> 2) & 3) * 256;
        ck = slot >> 4;                         // 0..3
        if (MODE == 1) {
            if (ck >= 2) { Ap = A1; Bp = B1 + (size_t)pn * 128 * 4096; kbase = (ck - 2) * 2048; }
            else         { Ap = A0; Bp = B0 + (size_t)pn * 128 * 4096; kbase = ck * 2048; }
        } else {
            Ap = A0; Bp = B0 + (size_t)pn * 128 * 4096; kbase = ck * 1024;
        }
        bncol = pn * 128;
        NW = 4096;
    }

    const int NT = (MODE == 0) ? 32 : 64;

    const int tid = threadIdx.x;
    const int wv = tid >> 6, lane = tid & 63;
    const int l15 = lane & 15, l4 = lane >> 4;
    const int fr = l15, fc = l4 * 8;
    const int wm = wv >> 1, wn = wv & 1;

    f32x4 acc[4][4] = {};

    auto stage = [&](int buf, int t) {
        const int kk = kbase + t * 32;
        gl16(Ap + (size_t)(bm + (wv * 2 + 0) * 16 + fr) * 4096 + kk + fc, &As[buf][(wv * 2 + 0) * 512]);
        gl16(Ap + (size_t)(bm + (wv * 2 + 1) * 16 + fr) * 4096 + kk + fc, &As[buf][(wv * 2 + 1) * 512]);
        gl16(Bp + (size_t)(wv * 16 + fr) * 4096 + kk + fc, &Bs[buf][wv * 512]);
    };
    auto compute = [&](int buf) {
        f16x8 xf[4], yf[4];
#pragma unroll
        for (int m = 0; m < 4; ++m)
            xf[m] = *(f16x8*)&As[buf][(wm * 4 + m) * 512 + lane * 8];
#pragma unroll
        for (int n = 0; n < 4; ++n)
            yf[n] = *(f16x8*)&Bs[buf][(wn * 4 + n) * 512 + lane * 8];
#pragma unroll
        for (int m = 0; m < 4; ++m)
#pragma unroll
            for (int n = 0; n < 4; ++n)
                acc[m][n] = __builtin_amdgcn_mfma_f32_16x16x32_f16(xf[m], yf[n], acc[m][n], 0, 0, 0);
    };

    stage(0, 0);
    __syncthreads();
    for (int t = 0; t < NT; ++t) {
        const int cur = t & 1;
        if (t + 1 < NT) stage(cur ^ 1, t + 1);
        compute(cur);
        __syncthreads();
    }

    short* Pc = P + (size_t)ck * 1024 * NW;
#pragma unroll
    for (int m = 0; m < 4; ++m)
#pragma unroll
        for (int n = 0; n < 4; ++n)
#pragma unroll
            for (int r = 0; r < 4; ++r) {
                int row = bm + wm * 64 + m * 16 + l4 * 4 + r;
                int col = bncol + wn * 64 + n * 16 + l15;
                Pc[(size_t)row * NW + col] = f32_to_f16s(acc[m][n][r]);
            }
}

// =====================================================================
// Gradient bt-GEMMs on TRANSPOSED operands (pos-Y pre-negated). Exact.
// =====================================================================
__global__ __launch_bounds__(512, 2) void grad2(
    const short* __restrict__ XnT, const short* __restrict__ YnT,
    const short* __restrict__ XpT, const short* __restrict__ YpT,
    float* __restrict__ Out)
{
    __shared__ __align__(1024) short As[2][16 * 512];
    __shared__ __align__(1024) short Bs[2][8 * 512];

    const int bid = blockIdx.x;
    const int xcd = bid & 7, slot = bid >> 3;
    const int pn = xcd * 4 + (slot & 3);
    const int bm = (slot >> 2) * 256;

    const int tid = threadIdx.x;
    const int wv = tid >> 6, lane = tid & 63;
    const int l15 = lane & 15, l4 = lane >> 4;
    const int fr = l15, fc = l4 * 8;
    const int wm = wv >> 1, wn = wv & 1;

    f32x4 acc[4][4] = {};

    auto stage = [&](int buf, int t) {
        const short* X = (t < 32) ? XnT : XpT;
        const short* Y = (t < 32) ? YnT : YpT;
        const int kk = (t & 31) * 32;
        gl16(X + (size_t)(bm + (wv * 2 + 0) * 16 + fr) * 1024 + kk + fc, &As[buf][(wv * 2 + 0) * 512]);
        gl16(X + (size_t)(bm + (wv * 2 + 1) * 16 + fr) * 1024 + kk + fc, &As[buf][(wv * 2 + 1) * 512]);
        gl16(Y + (size_t)(pn * 128 + wv * 16 + fr) * 1024 + kk + fc, &Bs[buf][wv * 512]);
    };
    auto compute = [&](int buf) {
        f16x8 xf[4], yf[4];
#pragma unroll
        for (int m = 0; m < 4; ++m)
            xf[m] = *(f16x8*)&As[buf][(wm * 4 + m) * 512 + lane * 8];
#pragma unroll
        for (int n = 0; n < 4; ++n)
            yf[n] = *(f16x8*)&Bs[buf][(wn * 4 + n) * 512 + lane * 8];
#pragma unroll
        for (int m = 0; m < 4; ++m)
#pragma unroll
            for (int n = 0; n < 4; ++n)
                acc[m][n] = __builtin_amdgcn_mfma_f32_16x16x32_f16(xf[m], yf[n], acc[m][n], 0, 0, 0);
    };

    stage(0, 0);
    __syncthreads();
    for (int t = 0; t < 64; ++t) {
        const int cur = t & 1;
        if (t + 1 < 64) stage(cur ^ 1, t + 1);
        compute(cur);
        __syncthreads();
    }

    const float invB = 1.0f / 1024.0f;
#pragma unroll
    for (int m = 0; m < 4; ++m)
#pragma unroll
        for (int n = 0; n < 4; ++n)
#pragma unroll
            for (int r = 0; r < 4; ++r) {
                int i_ = bm + wm * 64 + m * 16 + l4 * 4 + r;
                int j_ = pn * 128 + wn * 64 + n * 16 + l15;
                Out[(size_t)i_ * 4096 + j_] = acc[m][n][r] * invB;
            }
}

__global__ __launch_bounds__(256, 4) void grad1(
    const short* __restrict__ XnT, const short* __restrict__ YnT,
    const short* __restrict__ XpT, const short* __restrict__ YpT,
    float* __restrict__ Out)
{
    __shared__ __align__(1024) short As[2][8 * 512];
    __shared__ __align__(1024) short Bs[2][8 * 512];

    const int bid = blockIdx.x;
    const int xcd = bid & 7, slot = bid >> 3;
    const int pn = xcd * 2 + (slot & 1);
    const int bm = (slot >> 1) * 128;

    const int tid = threadIdx.x;
    const int wv = tid >> 6, lane = tid & 63;
    const int l15 = lane & 15, l4 = lane >> 4;
    const int fr = l15, fc = l4 * 8;
    const int wm = wv >> 1, wn = wv & 1;

    f32x4 acc[4][4] = {};

    auto stage = [&](int buf, int t) {
        const short* X = (t < 32) ? XnT : XpT;
        const short* Y = (t < 32) ? YnT : YpT;
        const int kk = (t & 31) * 32;
#pragma unroll
        for (int c = 0; c < 2; ++c) {
            int sub = wv * 2 + c;
            gl16(X + (size_t)(bm + sub * 16 + fr) * 1024 + kk + fc, &As[buf][sub * 512]);
            gl16(Y + (size_t)(pn * 128 + sub * 16 + fr) * 1024 + kk + fc, &Bs[buf][sub * 512]);
        }
    };
    auto compute = [&](int buf) {
        f16x8 xf[4], yf[4];
#pragma unroll
        for (int m = 0; m < 4; ++m)
            xf[m] = *(f16x8*)&As[buf][(wm * 4 + m) * 512 + lane * 8];
#pragma unroll
        for (int n = 0; n < 4; ++n)
            yf[n] = *(f16x8*)&Bs[buf][(wn * 4 + n) * 512 + lane * 8];
#pragma unroll
        for (int m = 0; m < 4; ++m)
#pragma unroll
            for (int n = 0; n < 4; ++n)
                acc[m][n] = __builtin_amdgcn_mfma_f32_16x16x32_f16(xf[m], yf[n], acc[m][n], 0, 0, 0);
    };

    stage(0, 0);
    __syncthreads();
    for (int t = 0; t < 64; ++t) {
        const int cur = t & 1;
        if (t + 1 < 64) stage(cur ^ 1, t + 1);
        compute(cur);
        __syncthreads();
    }

    const float invB = 1.0f / 1024.0f;
#pragma unroll
    for (int m = 0; m < 4; ++m)
#pragma unroll
        for (int n = 0; n < 4; ++n)
#pragma unroll
            for (int r = 0; r < 4; ++r) {
                int i_ = bm + wm * 64 + m * 16 + l4 * 4 + r;
                int j_ = pn * 128 + wn * 64 + n * 16 + l15;
                Out[(size_t)i_ * 4096 + 2 * j_ + 1] = acc[m][n][r] * invB;
                Out[(size_t)i_ * 4096 + 2 * j_]     = 0.0f;
            }
}

// ---------------- combine + sample (N=4096 logits, fp16 partials) ----------------
template<int EPI, int NC>
__global__ __launch_bounds__(256) void combine_h(
    const short* __restrict__ P, const float* __restrict__ bias,
    short* __restrict__ O0, short* __restrict__ O1,
    uint32_t k0, uint32_t k1)
{
    size_t e0 = ((size_t)blockIdx.x * 256 + threadIdx.x) * 8;
    float s[8] = {};
#pragma unroll
    for (int c = 0; c < NC; ++c) {
        f16x8 v = *(const f16x8*)(P + (size_t)c * 4194304 + e0);
#pragma unroll
        for (int j = 0; j < 8; ++j) s[j] += (float)v[j];
    }
    int col = (int)(e0 & 4095);
    short o[8];
#pragma unroll
    for (int j = 0; j < 8; ++j) {
        float v = s[j] + bias[col + j];
        float pr = sigmoidf_(v);
        float u = tf_uniform01(k0, k1, (uint32_t)(e0 + j));
        o[j] = (u < pr) ? F16_ONE : (short)0;
    }
    *(bf16x8*)&O0[e0] = *(bf16x8*)o;
    if (EPI == 1) *(bf16x8*)&O1[e0] = *(bf16x8*)o;
}

// ---------------- combine + sample (dual N=6144: h2 | pv-sign) ----------------
__global__ __launch_bounds__(256) void combine_dual(
    const short* __restrict__ P,
    const float* __restrict__ b_h2, const float* __restrict__ b_v,
    const float* __restrict__ occ,
    short* __restrict__ h2n, short* __restrict__ vneg,
    uint32_t kb0, uint32_t kb1, uint32_t kc0, uint32_t kc1)
{
    int idx = blockIdx.x * 256 + threadIdx.x;   // 0..786431
    int row = idx / 768;
    int cl  = (idx - row * 768) * 8;            // 0..6136
    float s[8] = {};
#pragma unroll
    for (int c = 0; c < 2; ++c) {
        f16x8 v = *(const f16x8*)(P + (size_t)c * 6291456 + (size_t)row * 6144 + cl);
#pragma unroll
        for (int j = 0; j < 8; ++j) s[j] += (float)v[j];
    }
    if (cl < 4096) {
        short o[8];
#pragma unroll
        for (int j = 0; j < 8; ++j) {
            float v = s[j] + b_h2[cl + j];
            float pr = sigmoidf_(v);
            size_t e = (size_t)row * 4096 + cl + j;
            float u = tf_uniform01(kb0, kb1, (uint32_t)e);
            o[j] = (u < pr) ? F16_ONE : (short)0;
        }
        *(bf16x8*)&h2n[(size_t)row * 4096 + cl] = *(bf16x8*)o;
    } else {
        int s0 = cl - 4096;                     // sign base, multiple of 8
        short o[16];
#pragma unroll
        for (int j = 0; j < 8; ++j) {
            int si = s0 + j;
            float v = s[j] + b_v[2 * si + 1];
            float pr = sigmoidf_(v);
            float u = tf_uniform01(kc0, kc1, (uint32_t)(row * 2048 + si));
            o[2 * j]     = (occ[(size_t)row * 2048 + si] != 0.0f) ? F16_ONE : (short)0;
            o[2 * j + 1] = (u < pr) ? F16_ONE : (short)0;
        }
        *(bf16x8*)&vneg[(size_t)row * 4096 + 2 * s0]     = *(bf16x8*)&o[0];
        *(bf16x8*)&vneg[(size_t)row * 4096 + 2 * s0 + 8] = *(bf16x8*)&o[8];
    }
}

// ---------------- small kernels ----------------
__global__ void cvt_kernel(const float* __restrict__ in, short* __restrict__ out, int n)
{
    int e = blockIdx.x * 256 + threadIdx.x;
    if (e < n) out[e] = (in[e] != 0.0f) ? F16_ONE : (short)0;
}

__global__ void dbv_fast(const float* __restrict__ vdata, const short* __restrict__ vneg,
                         float* __restrict__ out)
{
    __shared__ float part[4][64];
    int c = threadIdx.x & 63, rg = threadIdx.x >> 6;
    int s = blockIdx.x * 64 + c;
    float acc = 0.0f;
    for (int b = rg; b < B_SZ; b += 4)
        acc += ((vneg[(size_t)b * NV + 2 * s + 1] != 0) ? 1.0f : 0.0f)
             - vdata[(size_t)b * NV + 2 * s + 1];
    part[rg][c] = acc;
    __syncthreads();
    if (rg == 0) {
        out[2 * s + 1] = (part[0][c] + part[1][c] + part[2][c] + part[3][c]) * (1.0f / 1024.0f);
        out[2 * s] = 0.0f;
    }
}

__global__ void dbh_fast(const short* __restrict__ Xp, const short* __restrict__ Xn,
                         float* __restrict__ out)
{
    __shared__ int part[4][64];
    int c = threadIdx.x & 63, rg = threadIdx.x >> 6;
    int j = blockIdx.x * 64 + c;
    int acc = 0;
    for (int b = rg; b < B_SZ; b += 4)
        acc += (int)(Xn[(size_t)b * NH + j] != 0) - (int)(Xp[(size_t)b * NH + j] != 0);
    part[rg][c] = acc;
    __syncthreads();
    if (rg == 0)
        out[j] = (float)(part[0][c] + part[1][c] + part[2][c] + part[3][c]) * (1.0f / 1024.0f);
}

__global__ void zero_kernel(unsigned* p) { *p = 0u; }

__global__ void loss_count2(const float* __restrict__ vdata,
                            const short* __restrict__ vneg, unsigned* cnt)
{
    __shared__ int part[4];
    int t = blockIdx.x * 256 + threadIdx.x;
    int local = 0;
#pragma unroll
    for (int it = 0; it < 8; ++it) {
        int e = t + it * 262144;
        int b = e >> 11, s = e & 2047;
        float st = vdata[(size_t)b * NV + 2 * s + 1];
        float sp = (vneg[(size_t)b * NV + 2 * s + 1] != 0) ? 1.0f : 0.0f;
        local += (st != sp) ? 1 : 0;
    }
#pragma unroll
    for (int off = 32; off; off >>= 1) local += __shfl_down(local, off, 64);
    if ((threadIdx.x & 63) == 0) part[threadIdx.x >> 6] = local;
    __syncthreads();
    if (threadIdx.x == 0)
        atomicAdd(cnt, (unsigned)(part[0] + part[1] + part[2] + part[3]));
}

__global__ void loss_final_kernel(const unsigned* cnt, float* out, float lp, float lm)
{
    float mis = (float)(*cnt);
    float mat = 2097152.0f - mis;
    out[0] = -((mat * lp + mis * lm) * (1.0f / 2097152.0f));
}

// ---------------- host ----------------
extern "C" void kernel_launch(void* const* d_in, const int* in_sizes, int n_in,
                              void* d_out, int out_size, void* d_ws, size_t ws_size,
                              hipStream_t stream)
{
    (void)in_sizes; (void)n_in; (void)out_size; (void)ws_size;
    const float* v_data = (const float*)d_in[0];
    const float* occ    = (const float*)d_in[1];
    const float* W1     = (const float*)d_in[2];
    const float* b_v    = (const float*)d_in[3];
    const float* b_h1   = (const float*)d_in[4];
    const float* W2     = (const float*)d_in[5];
    const float* b_h2   = (const float*)d_in[6];
    float* out = (float*)d_out;

    char* w = (char*)d_ws;
    short* vneg = (short*)w;                            // 5 x 8 MB fp16 states
    short* h1d  = vneg + (size_t)B_SZ * NV;
    short* h2d  = h1d  + (size_t)B_SZ * NH;
    short* h1c  = h2d  + (size_t)B_SZ * NH;
    short* h2n  = h1c  + (size_t)B_SZ * NH;
    short* P    = h2n + (size_t)B_SZ * NH;              // 40 MB fp16 partials / grad-T
    unsigned* cnt = (unsigned*)(P + (size_t)20 * 1024 * 1024);

    // Transposed gradient operands alias P (dead after last combine).
    short* h1cT  = P;                                   // [4096][1024]
    short* h1dT  = h1cT  + (size_t)4096 * 1024;
    short* h2nT  = h1dT  + (size_t)4096 * 1024;
    short* h2dTn = h2nT  + (size_t)4096 * 1024;         // negated
    short* vsT   = h2dTn + (size_t)4096 * 1024;         // [2048][1024]
    short* vdsTn = vsT   + (size_t)2048 * 1024;         // negated

    // d_out as fp16 weight scratch: W1f 32 + W1To 16 + W2f 32 + W2T 32 = 112 MB
    short* W1f  = (short*)(((uintptr_t)(out + 1) + 15) & ~(uintptr_t)15);
    short* W1To = W1f  + (size_t)NH * NV;
    short* W2f  = W1To + (size_t)NSGN * NV;
    short* W2T  = W2f  + (size_t)NH * NH;

    // ---- JAX key derivation ----
    const uint32_t r0 = 0u, r1 = 42u;
    uint32_t kp1a, kp1b, kp2a, kp2b, kfa, kfb, kla, klb;
    tf2x32(r0, r1, 0u, 0u, kp1a, kp1b);
    tf2x32(r0, r1, 0u, 1u, kp2a, kp2b);
    tf2x32(r0, r1, 0u, 2u, kfa, kfb);
    tf2x32(r0, r1, 0u, 3u, kla, klb);
    uint32_t kaA[2], kaB[2], kbA[2], kbB[2], kcA[2], kcB[2];
    for (int i = 0; i < 2; ++i) {
        uint32_t fa, fb;
        tf2x32(kla, klb, 0u, (uint32_t)i, fa, fb);
        tf2x32(fa, fb, 0u, 0u, kaA[i], kaB[i]);
        tf2x32(fa, fb, 0u, 1u, kbA[i], kbB[i]);
        tf2x32(fa, fb, 0u, 2u, kcA[i], kcB[i]);
    }

    const int T = 256;
    const int NELEM = B_SZ * NH;

    conv_f16<<<(NH * NV) / (4 * 256), 256, 0, stream>>>(W1, W1f);
    conv_trodd<<<dim3(32, 64), 256, 0, stream>>>(W1, W1To);
    conv_tr<<<dim3(64, 64), 256, 0, stream>>>(W2, W2f, W2T);

    cvt_kernel<<<NELEM / T, T, 0, stream>>>(v_data, vneg, NELEM);

    // positive phase
    mm_chunk<0><<<512, 512, 0, stream>>>(vneg, nullptr, W1f, nullptr, P);
    combine_h<0, 4><<<2048, 256, 0, stream>>>(P, b_h1, h1d, nullptr, kp1a, kp1b);
    mm_chunk<0><<<512, 512, 0, stream>>>(h1d, nullptr, W2f, nullptr, P);
    combine_h<1, 4><<<2048, 256, 0, stream>>>(P, b_h2, h2d, h2n, kp2a, kp2b);

    // Gibbs loop (k = 2)
    for (int i = 0; i < 2; ++i) {
        mm_chunk<1><<<512, 512, 0, stream>>>(vneg, h2n, W1f, W2T, P);
        combine_h<0, 4><<<2048, 256, 0, stream>>>(P, b_h1, h1c, nullptr, kaA[i], kaB[i]);
        mm_chunk<2><<<384, 512, 0, stream>>>(h1c, nullptr, W2f, W1To, P);
        combine_dual<<<3072, 256, 0, stream>>>(P, b_h2, b_v, occ, h2n, vneg,
                                               kbA[i], kbB[i], kcA[i], kcB[i]);
    }

    // final hidden refresh
    mm_chunk<1><<<512, 512, 0, stream>>>(vneg, h2n, W1f, W2T, P);
    combine_h<0, 4><<<2048, 256, 0, stream>>>(P, b_h1, h1c, nullptr, kfa, kfb);

    // ---- gradients (transposed bt path; P now dead, reused) ----
    float* dW1o  = out + 1;
    float* dbvo  = dW1o + (size_t)NH * NV;
    float* dbh1o = dbvo + NV;
    float* dW2o  = dbh1o + NH;
    float* dbh2o = dW2o + (size_t)NH * NH;

    dim3 gT16(64, 16), gTS(32, 16);
    tr16<0><<<gT16, 256, 0, stream>>>(h1c, h1cT);
    tr16<0><<<gT16, 256, 0, stream>>>(h1d, h1dT);
    tr16<0><<<gT16, 256, 0, stream>>>(h2n, h2nT);
    tr16<1><<<gT16, 256, 0, stream>>>(h2d, h2dTn);
    tr_sign<<<gTS, 256, 0, stream>>>(vneg, vsT);
    tr_signf<<<gTS, 256, 0, stream>>>(v_data, vdsTn);

    grad1<<<512, 256, 0, stream>>>(h1cT, vsT, h1dT, vdsTn, dW1o);
    grad2<<<512, 512, 0, stream>>>(h1cT, h2nT, h1dT, h2dTn, dW2o);

    dbv_fast<<<NSGN / 64, T, 0, stream>>>(v_data, vneg, dbvo);
    dbh_fast<<<NH / 64, T, 0, stream>>>(h1d, h1c, dbh1o);
    dbh_fast<<<NH / 64, T, 0, stream>>>(h2d, h2n, dbh2o);

    zero_kernel<<<1, 1, 0, stream>>>(cnt);
    loss_count2<<<1024, T, 0, stream>>>(v_data, vneg, cnt);
    loss_final_kernel<<<1, 1, 0, stream>>>(cnt, out, logf(1.0f + 1e-7f), logf(1e-7f));
}

// Round 18
// 1129.388 us; speedup vs baseline: 1.2846x; 1.0478x over previous
//
#include <hip/hip_runtime.h>
#include <stdint.h>
#include <math.h>

#define B_SZ 1024
#define NV   4096
#define NH   4096
#define NSGN 2048

typedef short bf16x8 __attribute__((ext_vector_type(8)));
typedef short bf16x4 __attribute__((ext_vector_type(4)));
typedef float f32x4  __attribute__((ext_vector_type(4)));
typedef _Float16 f16x8 __attribute__((ext_vector_type(8)));
typedef unsigned char uchar;

#define F16_ONE  ((short)0x3C00)
#define F8_ONE   ((uchar)0x38)
#define F8_NEG1  ((uchar)0xB8)

__device__ __forceinline__ short f32_to_f16s(float f)
{
    union { _Float16 h; short s; } u;
    u.h = (_Float16)f;
    return u.s;
}

// ---------------- threefry2x32 (JAX-compatible, 20 rounds) ----------------
__host__ __device__ __forceinline__ void tf2x32(uint32_t k0, uint32_t k1,
                                                uint32_t x0, uint32_t x1,
                                                uint32_t& o0, uint32_t& o1)
{
    uint32_t k2 = k0 ^ k1 ^ 0x1BD11BDAu;
#define TFR(r) { x0 += x1; x1 = (x1 << (r)) | (x1 >> (32 - (r))); x1 ^= x0; }
    x0 += k0; x1 += k1;
    TFR(13) TFR(15) TFR(26) TFR(6)
    x0 += k1; x1 += k2 + 1u;
    TFR(17) TFR(29) TFR(16) TFR(24)
    x0 += k2; x1 += k0 + 2u;
    TFR(13) TFR(15) TFR(26) TFR(6)
    x0 += k0; x1 += k1 + 3u;
    TFR(17) TFR(29) TFR(16) TFR(24)
    x0 += k1; x1 += k2 + 4u;
    TFR(13) TFR(15) TFR(26) TFR(6)
    x0 += k2; x1 += k0 + 5u;
#undef TFR
    o0 = x0; o1 = x1;
}

__device__ __forceinline__ float tf_uniform01(uint32_t k0, uint32_t k1, uint32_t idx)
{
    uint32_t a, b;
    tf2x32(k0, k1, 0u, idx, a, b);
    uint32_t bits = a ^ b;
    uint32_t fb = (bits >> 9) | 0x3F800000u;
    return __uint_as_float(fb) - 1.0f;
}

__device__ __forceinline__ float sigmoidf_(float x)
{
    if (x >= 0.0f) { float e = expf(-x); return 1.0f / (1.0f + e); }
    float e = expf(x); return e / (1.0f + e);
}

__device__ __forceinline__ void gl16(const void* g, void* l)
{
    __builtin_amdgcn_global_load_lds((const __attribute__((address_space(1))) void*)g,
                                     (__attribute__((address_space(3))) void*)l, 16, 0, 0);
}

// ---------------- weight precompute ----------------
__global__ __launch_bounds__(256) void conv_tr(const float* __restrict__ W,
                                               short* __restrict__ Wf,
                                               short* __restrict__ Wt)
{
    __shared__ short t[64][65];
    const int bx = blockIdx.x * 64;
    const int by = blockIdx.y * 64;
    const int r0 = threadIdx.x >> 4;
    const int c0 = (threadIdx.x & 15) * 4;
#pragma unroll
    for (int i = 0; i < 4; ++i) {
        int row = by + r0 + i * 16;
        f32x4 v = *(const f32x4*)(W + (size_t)row * 4096 + bx + c0);
        short h[4];
#pragma unroll
        for (int j = 0; j < 4; ++j) h[j] = f32_to_f16s(v[j]);
        *(bf16x4*)(Wf + (size_t)row * 4096 + bx + c0) = *(bf16x4*)h;
#pragma unroll
        for (int j = 0; j < 4; ++j) t[c0 + j][r0 + i * 16] = h[j];
    }
    __syncthreads();
#pragma unroll
    for (int i = 0; i < 4; ++i) {
        int orow = r0 + i * 16;
        short o[4] = { t[orow][c0], t[orow][c0 + 1], t[orow][c0 + 2], t[orow][c0 + 3] };
        *(bf16x4*)(Wt + (size_t)(bx + orow) * 4096 + by + c0) = *(bf16x4*)o;
    }
}

__global__ __launch_bounds__(256) void conv_f16(const float* __restrict__ W,
                                                short* __restrict__ Wf)
{
    size_t i = ((size_t)blockIdx.x * 256 + threadIdx.x) * 4;
    f32x4 v = *(const f32x4*)(W + i);
    short h[4];
#pragma unroll
    for (int c = 0; c < 4; ++c) h[c] = f32_to_f16s(v[c]);
    *(bf16x4*)(Wf + i) = *(bf16x4*)h;
}

__global__ __launch_bounds__(256) void conv_trodd(const float* __restrict__ W,
                                                  short* __restrict__ Wt)
{
    __shared__ short t[64][65];
    const int bx = blockIdx.x * 64;
    const int by = blockIdx.y * 64;
    const int r0 = threadIdx.x >> 4;
    const int c0 = (threadIdx.x & 15) * 4;
#pragma unroll
    for (int i = 0; i < 4; ++i) {
        int row = by + r0 + i * 16;
        const float* p = W + (size_t)row * 4096 + 2 * (bx + c0);
        f32x4 a = *(const f32x4*)p;
        f32x4 b = *(const f32x4*)(p + 4);
        t[c0 + 0][r0 + i * 16] = f32_to_f16s(a[1]);
        t[c0 + 1][r0 + i * 16] = f32_to_f16s(a[3]);
        t[c0 + 2][r0 + i * 16] = f32_to_f16s(b[1]);
        t[c0 + 3][r0 + i * 16] = f32_to_f16s(b[3]);
    }
    __syncthreads();
#pragma unroll
    for (int i = 0; i < 4; ++i) {
        int orow = r0 + i * 16;
        short o[4] = { t[orow][c0], t[orow][c0 + 1], t[orow][c0 + 2], t[orow][c0 + 3] };
        *(bf16x4*)(Wt + (size_t)(bx + orow) * 4096 + by + c0) = *(bf16x4*)o;
    }
}

// ---------------- state transposes -> FP8 (for gradient bt-GEMMs) ----------------
// fp16 state [1024][4096] -> fp8 [4096][1024]; value 0x38 (1.0) or 0xB8 (-1.0 if NEG)
template<int NEG>
__global__ __launch_bounds__(256) void tr8(const short* __restrict__ in,
                                           uchar* __restrict__ out)
{
    __shared__ uchar t[64][68];
    const int bx = blockIdx.x * 64;
    const int by = blockIdx.y * 64;
    const int r0 = threadIdx.x >> 4;
    const int c0 = (threadIdx.x & 15) * 4;
    const uchar ONE = NEG ? F8_NEG1 : F8_ONE;
#pragma unroll
    for (int i = 0; i < 4; ++i) {
        int row = by + r0 + i * 16;
        bf16x4 v = *(const bf16x4*)(in + (size_t)row * 4096 + bx + c0);
#pragma unroll
        for (int j = 0; j < 4; ++j)
            t[c0 + j][r0 + i * 16] = (v[j] != 0) ? ONE : (uchar)0;
    }
    __syncthreads();
#pragma unroll
    for (int i = 0; i < 4; ++i) {
        int orow = r0 + i * 16;
        uchar o[4] = { t[orow][c0], t[orow][c0 + 1], t[orow][c0 + 2], t[orow][c0 + 3] };
        *(uint32_t*)(out + (size_t)(bx + orow) * 1024 + by + c0) = *(uint32_t*)o;
    }
}

// vneg fp16 [1024][4096] odd cols -> fp8 [2048][1024]
__global__ __launch_bounds__(256) void tr_sign8(const short* __restrict__ in,
                                                uchar* __restrict__ out)
{
    __shared__ uchar t[64][68];
    const int bx = blockIdx.x * 64;
    const int by = blockIdx.y * 64;
    const int r0 = threadIdx.x >> 4;
    const int c0 = (threadIdx.x & 15) * 4;
#pragma unroll
    for (int i = 0; i < 4; ++i) {
        int row = by + r0 + i * 16;
        bf16x8 v = *(const bf16x8*)(in + (size_t)row * 4096 + 2 * (bx + c0));
#pragma unroll
        for (int j = 0; j < 4; ++j)
            t[c0 + j][r0 + i * 16] = (v[2 * j + 1] != 0) ? F8_ONE : (uchar)0;
    }
    __syncthreads();
#pragma unroll
    for (int i = 0; i < 4; ++i) {
        int orow = r0 + i * 16;
        uchar o[4] = { t[orow][c0], t[orow][c0 + 1], t[orow][c0 + 2], t[orow][c0 + 3] };
        *(uint32_t*)(out + (size_t)(bx + orow) * 1024 + by + c0) = *(uint32_t*)o;
    }
}

// v_data f32 [1024][4096] odd cols -> fp8 [2048][1024], NEGATED
__global__ __launch_bounds__(256) void tr_signf8(const float* __restrict__ in,
                                                 uchar* __restrict__ out)
{
    __shared__ uchar t[64][68];
    const int bx = blockIdx.x * 64;
    const int by = blockIdx.y * 64;
    const int r0 = threadIdx.x >> 4;
    const int c0 = (threadIdx.x & 15) * 4;
#pragma unroll
    for (int i = 0; i < 4; ++i) {
        int row = by + r0 + i * 16;
        const float* p = in + (size_t)row * 4096 + 2 * (bx + c0);
        f32x4 a = *(const f32x4*)p;
        f32x4 b = *(const f32x4*)(p + 4);
        t[c0 + 0][r0 + i * 16] = (a[1] != 0.0f) ? F8_NEG1 : (uchar)0;
        t[c0 + 1][r0 + i * 16] = (a[3] != 0.0f) ? F8_NEG1 : (uchar)0;
        t[c0 + 2][r0 + i * 16] = (b[1] != 0.0f) ? F8_NEG1 : (uchar)0;
        t[c0 + 3][r0 + i * 16] = (b[3] != 0.0f) ? F8_NEG1 : (uchar)0;
    }
    __syncthreads();
#pragma unroll
    for (int i = 0; i < 4; ++i) {
        int orow = r0 + i * 16;
        uchar o[4] = { t[orow][c0], t[orow][c0 + 1], t[orow][c0 + 2], t[orow][c0 + 3] };
        *(uint32_t*)(out + (size_t)(bx + orow) * 1024 + by + c0) = *(uint32_t*)o;
    }
}

// =====================================================================
// Chunk GEMM (fp16), 256(M) x 128(N) tile, BK=32, 512 thr = 8 waves,
// 48 KB LDS dbuf. Writes FP16 partials P[ck][1024][NW]. Unchanged.
// =====================================================================
template<int MODE>
__global__ __launch_bounds__(512, 2) void mm_chunk(
    const short* __restrict__ A0, const short* __restrict__ A1,
    const short* __restrict__ B0, const short* __restrict__ B1,
    short* __restrict__ P)
{
    __shared__ __align__(1024) short As[2][16 * 512];
    __shared__ __align__(1024) short Bs[2][8 * 512];

    const int bid = blockIdx.x;
    const int xcd = bid & 7, slot = bid >> 3;

    int bm, bncol, ck, kbase, NW;
    const short* Ap;
    const short* Bp;
    if (MODE == 2) {
        int slot6 = slot % 6, rest = slot / 6;
        int pn = xcd * 6 + slot6;
        bm = (rest & 3) * 256;
        ck = rest >> 2;
        kbase = ck * 2048;
        Ap = A0;
        Bp = (pn < 32) ? (B0 + (size_t)pn * 128 * 4096)
                       : (B1 + (size_t)(pn - 32) * 128 * 4096);
        bncol = pn * 128;
        NW = 6144;
    } else {
        int pn = xcd * 4 + (slot & 3);
        bm = ((slot >> 2) & 3) * 256;
        ck = slot >> 4;
        if (MODE == 1) {
            if (ck >= 2) { Ap = A1; Bp = B1 + (size_t)pn * 128 * 4096; kbase = (ck - 2) * 2048; }
            else         { Ap = A0; Bp = B0 + (size_t)pn * 128 * 4096; kbase = ck * 2048; }
        } else {
            Ap = A0; Bp = B0 + (size_t)pn * 128 * 4096; kbase = ck * 1024;
        }
        bncol = pn * 128;
        NW = 4096;
    }

    const int NT = (MODE == 0) ? 32 : 64;

    const int tid = threadIdx.x;
    const int wv = tid >> 6, lane = tid & 63;
    const int l15 = lane & 15, l4 = lane >> 4;
    const int fr = l15, fc = l4 * 8;
    const int wm = wv >> 1, wn = wv & 1;

    f32x4 acc[4][4] = {};

    auto stage = [&](int buf, int t) {
        const int kk = kbase + t * 32;
        gl16(Ap + (size_t)(bm + (wv * 2 + 0) * 16 + fr) * 4096 + kk + fc, &As[buf][(wv * 2 + 0) * 512]);
        gl16(Ap + (size_t)(bm + (wv * 2 + 1) * 16 + fr) * 4096 + kk + fc, &As[buf][(wv * 2 + 1) * 512]);
        gl16(Bp + (size_t)(wv * 16 + fr) * 4096 + kk + fc, &Bs[buf][wv * 512]);
    };
    auto compute = [&](int buf) {
        f16x8 xf[4], yf[4];
#pragma unroll
        for (int m = 0; m < 4; ++m)
            xf[m] = *(f16x8*)&As[buf][(wm * 4 + m) * 512 + lane * 8];
#pragma unroll
        for (int n = 0; n < 4; ++n)
            yf[n] = *(f16x8*)&Bs[buf][(wn * 4 + n) * 512 + lane * 8];
#pragma unroll
        for (int m = 0; m < 4; ++m)
#pragma unroll
            for (int n = 0; n < 4; ++n)
                acc[m][n] = __builtin_amdgcn_mfma_f32_16x16x32_f16(xf[m], yf[n], acc[m][n], 0, 0, 0);
    };

    stage(0, 0);
    __syncthreads();
    for (int t = 0; t < NT; ++t) {
        const int cur = t & 1;
        if (t + 1 < NT) stage(cur ^ 1, t + 1);
        compute(cur);
        __syncthreads();
    }

    short* Pc = P + (size_t)ck * 1024 * NW;
#pragma unroll
    for (int m = 0; m < 4; ++m)
#pragma unroll
        for (int n = 0; n < 4; ++n)
#pragma unroll
            for (int r = 0; r < 4; ++r) {
                int row = bm + wm * 64 + m * 16 + l4 * 4 + r;
                int col = bncol + wn * 64 + n * 16 + l15;
                Pc[(size_t)row * NW + col] = f32_to_f16s(acc[m][n][r]);
            }
}

// =====================================================================
// FP8 gradient bt-GEMMs on transposed operands (pos-Y pre-negated). Exact.
// Subtile = 16 rows x 32 k x 1B = 512 B; one gl16 stages TWO subtiles
// (lane>>5 selects). Fragment read: ds_read_b64 at
// sub*512 + (l4>>1)*256 + l15*16 + (l4&1)*8.
// =====================================================================
// dW2: 256x128 tile, 512 thr = 8 waves (4M x 2N), K-concat 2048
__global__ __launch_bounds__(512, 2) void grad2(
    const uchar* __restrict__ XnT, const uchar* __restrict__ YnT,
    const uchar* __restrict__ XpT, const uchar* __restrict__ YpT,
    float* __restrict__ Out)
{
    __shared__ __align__(1024) uchar As[2][16 * 512];
    __shared__ __align__(1024) uchar Bs[2][8 * 512];

    const int bid = blockIdx.x;
    const int xcd = bid & 7, slot = bid >> 3;
    const int pn = xcd * 4 + (slot & 3);
    const int bm = (slot >> 2) * 256;

    const int tid = threadIdx.x;
    const int wv = tid >> 6, lane = tid & 63;
    const int l15 = lane & 15, l4 = lane >> 4;
    const int sl = lane & 31, lh = lane >> 5;   // sub-lane, subtile-half
    const int wm = wv >> 1, wn = wv & 1;
    const int foff = (l4 >> 1) * 256 + l15 * 16 + (l4 & 1) * 8;

    f32x4 acc[4][4] = {};

    auto stage = [&](int buf, int t) {
        const uchar* X = (t < 32) ? XnT : XpT;
        const uchar* Y = (t < 32) ? YnT : YpT;
        const int kk = (t & 31) * 32;
        // A: 16 subtiles, wave wv stages subtiles 2wv,2wv+1 via one gl16
        gl16(X + (size_t)(bm + (2 * wv + lh) * 16 + (sl & 15)) * 1024 + kk + (sl >> 4) * 16,
             &As[buf][wv * 1024]);
        // B: 8 subtiles, waves 0..3 stage subtiles 2wv,2wv+1
        if (wv < 4)
            gl16(Y + (size_t)(pn * 128 + (2 * wv + lh) * 16 + (sl & 15)) * 1024 + kk + (sl >> 4) * 16,
                 &Bs[buf][wv * 1024]);
    };
    auto compute = [&](int buf) {
        long xf[4], yf[4];
#pragma unroll
        for (int m = 0; m < 4; ++m)
            xf[m] = *(long*)&As[buf][(wm * 4 + m) * 512 + foff];
#pragma unroll
        for (int n = 0; n < 4; ++n)
            yf[n] = *(long*)&Bs[buf][(wn * 4 + n) * 512 + foff];
#pragma unroll
        for (int m = 0; m < 4; ++m)
#pragma unroll
            for (int n = 0; n < 4; ++n)
                acc[m][n] = __builtin_amdgcn_mfma_f32_16x16x32_fp8_fp8(xf[m], yf[n], acc[m][n], 0, 0, 0);
    };

    stage(0, 0);
    __syncthreads();
    for (int t = 0; t < 64; ++t) {
        const int cur = t & 1;
        if (t + 1 < 64) stage(cur ^ 1, t + 1);
        compute(cur);
        __syncthreads();
    }

    const float invB = 1.0f / 1024.0f;
#pragma unroll
    for (int m = 0; m < 4; ++m)
#pragma unroll
        for (int n = 0; n < 4; ++n)
#pragma unroll
            for (int r = 0; r < 4; ++r) {
                int i_ = bm + wm * 64 + m * 16 + l4 * 4 + r;
                int j_ = pn * 128 + wn * 64 + n * 16 + l15;
                Out[(size_t)i_ * 4096 + j_] = acc[m][n][r] * invB;
            }
}

// dW1: 128x128 tile, 256 thr = 4 waves (2M x 2N of 64x64), N=2048 sign cols
__global__ __launch_bounds__(256, 4) void grad1(
    const uchar* __restrict__ XnT, const uchar* __restrict__ YnT,
    const uchar* __restrict__ XpT, const uchar* __restrict__ YpT,
    float* __restrict__ Out)
{
    __shared__ __align__(1024) uchar As[2][8 * 512];
    __shared__ __align__(1024) uchar Bs[2][8 * 512];

    const int bid = blockIdx.x;
    const int xcd = bid & 7, slot = bid >> 3;
    const int pn = xcd * 2 + (slot & 1);        // 0..15
    const int bm = (slot >> 1) * 128;           // 32 tiles

    const int tid = threadIdx.x;
    const int wv = tid >> 6, lane = tid & 63;
    const int l15 = lane & 15, l4 = lane >> 4;
    const int sl = lane & 31, lh = lane >> 5;
    const int wm = wv >> 1, wn = wv & 1;
    const int foff = (l4 >> 1) * 256 + l15 * 16 + (l4 & 1) * 8;

    f32x4 acc[4][4] = {};

    auto stage = [&](int buf, int t) {
        const uchar* X = (t < 32) ? XnT : XpT;
        const uchar* Y = (t < 32) ? YnT : YpT;
        const int kk = (t & 31) * 32;
        gl16(X + (size_t)(bm + (2 * wv + lh) * 16 + (sl & 15)) * 1024 + kk + (sl >> 4) * 16,
             &As[buf][wv * 1024]);
        gl16(Y + (size_t)(pn * 128 + (2 * wv + lh) * 16 + (sl & 15)) * 1024 + kk + (sl >> 4) * 16,
             &Bs[buf][wv * 1024]);
    };
    auto compute = [&](int buf) {
        long xf[4], yf[4];
#pragma unroll
        for (int m = 0; m < 4; ++m)
            xf[m] = *(long*)&As[buf][(wm * 4 + m) * 512 + foff];
#pragma unroll
        for (int n = 0; n < 4; ++n)
            yf[n] = *(long*)&Bs[buf][(wn * 4 + n) * 512 + foff];
#pragma unroll
        for (int m = 0; m < 4; ++m)
#pragma unroll
            for (int n = 0; n < 4; ++n)
                acc[m][n] = __builtin_amdgcn_mfma_f32_16x16x32_fp8_fp8(xf[m], yf[n], acc[m][n], 0, 0, 0);
    };

    stage(0, 0);
    __syncthreads();
    for (int t = 0; t < 64; ++t) {
        const int cur = t & 1;
        if (t + 1 < 64) stage(cur ^ 1, t + 1);
        compute(cur);
        __syncthreads();
    }

    const float invB = 1.0f / 1024.0f;
#pragma unroll
    for (int m = 0; m < 4; ++m)
#pragma unroll
        for (int n = 0; n < 4; ++n)
#pragma unroll
            for (int r = 0; r < 4; ++r) {
                int i_ = bm + wm * 64 + m * 16 + l4 * 4 + r;
                int j_ = pn * 128 + wn * 64 + n * 16 + l15;
                Out[(size_t)i_ * 4096 + 2 * j_ + 1] = acc[m][n][r] * invB;
                Out[(size_t)i_ * 4096 + 2 * j_]     = 0.0f;
            }
}

// ---------------- combine + sample (N=4096 logits, fp16 partials) ----------------
template<int EPI, int NC>
__global__ __launch_bounds__(256) void combine_h(
    const short* __restrict__ P, const float* __restrict__ bias,
    short* __restrict__ O0, short* __restrict__ O1,
    uint32_t k0, uint32_t k1)
{
    size_t e0 = ((size_t)blockIdx.x * 256 + threadIdx.x) * 8;
    float s[8] = {};
#pragma unroll
    for (int c = 0; c < NC; ++c) {
        f16x8 v = *(const f16x8*)(P + (size_t)c * 4194304 + e0);
#pragma unroll
        for (int j = 0; j < 8; ++j) s[j] += (float)v[j];
    }
    int col = (int)(e0 & 4095);
    short o[8];
#pragma unroll
    for (int j = 0; j < 8; ++j) {
        float v = s[j] + bias[col + j];
        float pr = sigmoidf_(v);
        float u = tf_uniform01(k0, k1, (uint32_t)(e0 + j));
        o[j] = (u < pr) ? F16_ONE : (short)0;
    }
    *(bf16x8*)&O0[e0] = *(bf16x8*)o;
    if (EPI == 1) *(bf16x8*)&O1[e0] = *(bf16x8*)o;
}

// ---------------- combine + sample (dual N=6144: h2 | pv-sign) ----------------
__global__ __launch_bounds__(256) void combine_dual(
    const short* __restrict__ P,
    const float* __restrict__ b_h2, const float* __restrict__ b_v,
    const float* __restrict__ occ,
    short* __restrict__ h2n, short* __restrict__ vneg,
    uint32_t kb0, uint32_t kb1, uint32_t kc0, uint32_t kc1)
{
    int idx = blockIdx.x * 256 + threadIdx.x;
    int row = idx / 768;
    int cl  = (idx - row * 768) * 8;
    float s[8] = {};
#pragma unroll
    for (int c = 0; c < 2; ++c) {
        f16x8 v = *(const f16x8*)(P + (size_t)c * 6291456 + (size_t)row * 6144 + cl);
#pragma unroll
        for (int j = 0; j < 8; ++j) s[j] += (float)v[j];
    }
    if (cl < 4096) {
        short o[8];
#pragma unroll
        for (int j = 0; j < 8; ++j) {
            float v = s[j] + b_h2[cl + j];
            float pr = sigmoidf_(v);
            size_t e = (size_t)row * 4096 + cl + j;
            float u = tf_uniform01(kb0, kb1, (uint32_t)e);
            o[j] = (u < pr) ? F16_ONE : (short)0;
        }
        *(bf16x8*)&h2n[(size_t)row * 4096 + cl] = *(bf16x8*)o;
    } else {
        int s0 = cl - 4096;
        short o[16];
#pragma unroll
        for (int j = 0; j < 8; ++j) {
            int si = s0 + j;
            float v = s[j] + b_v[2 * si + 1];
            float pr = sigmoidf_(v);
            float u = tf_uniform01(kc0, kc1, (uint32_t)(row * 2048 + si));
            o[2 * j]     = (occ[(size_t)row * 2048 + si] != 0.0f) ? F16_ONE : (short)0;
            o[2 * j + 1] = (u < pr) ? F16_ONE : (short)0;
        }
        *(bf16x8*)&vneg[(size_t)row * 4096 + 2 * s0]     = *(bf16x8*)&o[0];
        *(bf16x8*)&vneg[(size_t)row * 4096 + 2 * s0 + 8] = *(bf16x8*)&o[8];
    }
}

// ---------------- small kernels ----------------
__global__ void cvt_kernel(const float* __restrict__ in, short* __restrict__ out, int n)
{
    int e = blockIdx.x * 256 + threadIdx.x;
    if (e < n) out[e] = (in[e] != 0.0f) ? F16_ONE : (short)0;
}

__global__ void dbv_fast(const float* __restrict__ vdata, const short* __restrict__ vneg,
                         float* __restrict__ out)
{
    __shared__ float part[4][64];
    int c = threadIdx.x & 63, rg = threadIdx.x >> 6;
    int s = blockIdx.x * 64 + c;
    float acc = 0.0f;
    for (int b = rg; b < B_SZ; b += 4)
        acc += ((vneg[(size_t)b * NV + 2 * s + 1] != 0) ? 1.0f : 0.0f)
             - vdata[(size_t)b * NV + 2 * s + 1];
    part[rg][c] = acc;
    __syncthreads();
    if (rg == 0) {
        out[2 * s + 1] = (part[0][c] + part[1][c] + part[2][c] + part[3][c]) * (1.0f / 1024.0f);
        out[2 * s] = 0.0f;
    }
}

__global__ void dbh_fast(const short* __restrict__ Xp, const short* __restrict__ Xn,
                         float* __restrict__ out)
{
    __shared__ int part[4][64];
    int c = threadIdx.x & 63, rg = threadIdx.x >> 6;
    int j = blockIdx.x * 64 + c;
    int acc = 0;
    for (int b = rg; b < B_SZ; b += 4)
        acc += (int)(Xn[(size_t)b * NH + j] != 0) - (int)(Xp[(size_t)b * NH + j] != 0);
    part[rg][c] = acc;
    __syncthreads();
    if (rg == 0)
        out[j] = (float)(part[0][c] + part[1][c] + part[2][c] + part[3][c]) * (1.0f / 1024.0f);
}

__global__ void zero_kernel(unsigned* p) { *p = 0u; }

__global__ void loss_count2(const float* __restrict__ vdata,
                            const short* __restrict__ vneg, unsigned* cnt)
{
    __shared__ int part[4];
    int t = blockIdx.x * 256 + threadIdx.x;
    int local = 0;
#pragma unroll
    for (int it = 0; it < 8; ++it) {
        int e = t + it * 262144;
        int b = e >> 11, s = e & 2047;
        float st = vdata[(size_t)b * NV + 2 * s + 1];
        float sp = (vneg[(size_t)b * NV + 2 * s + 1] != 0) ? 1.0f : 0.0f;
        local += (st != sp) ? 1 : 0;
    }
#pragma unroll
    for (int off = 32; off; off >>= 1) local += __shfl_down(local, off, 64);
    if ((threadIdx.x & 63) == 0) part[threadIdx.x >> 6] = local;
    __syncthreads();
    if (threadIdx.x == 0)
        atomicAdd(cnt, (unsigned)(part[0] + part[1] + part[2] + part[3]));
}

__global__ void loss_final_kernel(const unsigned* cnt, float* out, float lp, float lm)
{
    float mis = (float)(*cnt);
    float mat = 2097152.0f - mis;
    out[0] = -((mat * lp + mis * lm) * (1.0f / 2097152.0f));
}

// ---------------- host ----------------
extern "C" void kernel_launch(void* const* d_in, const int* in_sizes, int n_in,
                              void* d_out, int out_size, void* d_ws, size_t ws_size,
                              hipStream_t stream)
{
    (void)in_sizes; (void)n_in; (void)out_size; (void)ws_size;
    const float* v_data = (const float*)d_in[0];
    const float* occ    = (const float*)d_in[1];
    const float* W1     = (const float*)d_in[2];
    const float* b_v    = (const float*)d_in[3];
    const float* b_h1   = (const float*)d_in[4];
    const float* W2     = (const float*)d_in[5];
    const float* b_h2   = (const float*)d_in[6];
    float* out = (float*)d_out;

    char* w = (char*)d_ws;
    short* vneg = (short*)w;
    short* h1d  = vneg + (size_t)B_SZ * NV;
    short* h2d  = h1d  + (size_t)B_SZ * NH;
    short* h1c  = h2d  + (size_t)B_SZ * NH;
    short* h2n  = h1c  + (size_t)B_SZ * NH;
    short* P    = h2n + (size_t)B_SZ * NH;              // 40 MB fp16 partials
    unsigned* cnt = (unsigned*)(P + (size_t)20 * 1024 * 1024);

    // FP8 transposed gradient operands alias P (dead after last combine).
    uchar* h1cT8  = (uchar*)P;                          // [4096][1024] = 4 MB
    uchar* h1dT8  = h1cT8  + (size_t)4096 * 1024;
    uchar* h2nT8  = h1dT8  + (size_t)4096 * 1024;
    uchar* h2dT8n = h2nT8  + (size_t)4096 * 1024;       // negated
    uchar* vsT8   = h2dT8n + (size_t)4096 * 1024;       // [2048][1024] = 2 MB
    uchar* vdsT8n = vsT8   + (size_t)2048 * 1024;       // negated

    // d_out as fp16 weight scratch: W1f 32 + W1To 16 + W2f 32 + W2T 32 = 112 MB
    short* W1f  = (short*)(((uintptr_t)(out + 1) + 15) & ~(uintptr_t)15);
    short* W1To = W1f  + (size_t)NH * NV;
    short* W2f  = W1To + (size_t)NSGN * NV;
    short* W2T  = W2f  + (size_t)NH * NH;

    // ---- JAX key derivation ----
    const uint32_t r0 = 0u, r1 = 42u;
    uint32_t kp1a, kp1b, kp2a, kp2b, kfa, kfb, kla, klb;
    tf2x32(r0, r1, 0u, 0u, kp1a, kp1b);
    tf2x32(r0, r1, 0u, 1u, kp2a, kp2b);
    tf2x32(r0, r1, 0u, 2u, kfa, kfb);
    tf2x32(r0, r1, 0u, 3u, kla, klb);
    uint32_t kaA[2], kaB[2], kbA[2], kbB[2], kcA[2], kcB[2];
    for (int i = 0; i < 2; ++i) {
        uint32_t fa, fb;
        tf2x32(kla, klb, 0u, (uint32_t)i, fa, fb);
        tf2x32(fa, fb, 0u, 0u, kaA[i], kaB[i]);
        tf2x32(fa, fb, 0u, 1u, kbA[i], kbB[i]);
        tf2x32(fa, fb, 0u, 2u, kcA[i], kcB[i]);
    }

    const int T = 256;
    const int NELEM = B_SZ * NH;

    conv_f16<<<(NH * NV) / (4 * 256), 256, 0, stream>>>(W1, W1f);
    conv_trodd<<<dim3(32, 64), 256, 0, stream>>>(W1, W1To);
    conv_tr<<<dim3(64, 64), 256, 0, stream>>>(W2, W2f, W2T);

    cvt_kernel<<<NELEM / T, T, 0, stream>>>(v_data, vneg, NELEM);

    // positive phase
    mm_chunk<0><<<512, 512, 0, stream>>>(vneg, nullptr, W1f, nullptr, P);
    combine_h<0, 4><<<2048, 256, 0, stream>>>(P, b_h1, h1d, nullptr, kp1a, kp1b);
    mm_chunk<0><<<512, 512, 0, stream>>>(h1d, nullptr, W2f, nullptr, P);
    combine_h<1, 4><<<2048, 256, 0, stream>>>(P, b_h2, h2d, h2n, kp2a, kp2b);

    // Gibbs loop (k = 2)
    for (int i = 0; i < 2; ++i) {
        mm_chunk<1><<<512, 512, 0, stream>>>(vneg, h2n, W1f, W2T, P);
        combine_h<0, 4><<<2048, 256, 0, stream>>>(P, b_h1, h1c, nullptr, kaA[i], kaB[i]);
        mm_chunk<2><<<384, 512, 0, stream>>>(h1c, nullptr, W2f, W1To, P);
        combine_dual<<<3072, 256, 0, stream>>>(P, b_h2, b_v, occ, h2n, vneg,
                                               kbA[i], kbB[i], kcA[i], kcB[i]);
    }

    // final hidden refresh
    mm_chunk<1><<<512, 512, 0, stream>>>(vneg, h2n, W1f, W2T, P);
    combine_h<0, 4><<<2048, 256, 0, stream>>>(P, b_h1, h1c, nullptr, kfa, kfb);

    // ---- gradients (fp8 transposed bt path; P dead, reused) ----
    float* dW1o  = out + 1;
    float* dbvo  = dW1o + (size_t)NH * NV;
    float* dbh1o = dbvo + NV;
    float* dW2o  = dbh1o + NH;
    float* dbh2o = dW2o + (size_t)NH * NH;

    dim3 gT16(64, 16), gTS(32, 16);
    tr8<0><<<gT16, 256, 0, stream>>>(h1c, h1cT8);
    tr8<0><<<gT16, 256, 0, stream>>>(h1d, h1dT8);
    tr8<0><<<gT16, 256, 0, stream>>>(h2n, h2nT8);
    tr8<1><<<gT16, 256, 0, stream>>>(h2d, h2dT8n);
    tr_sign8<<<gTS, 256, 0, stream>>>(vneg, vsT8);
    tr_signf8<<<gTS, 256, 0, stream>>>(v_data, vdsT8n);

    grad1<<<512, 256, 0, stream>>>(h1cT8, vsT8, h1dT8, vdsT8n, dW1o);
    grad2<<<512, 512, 0, stream>>>(h1cT8, h2nT8, h1dT8, h2dT8n, dW2o);

    dbv_fast<<<NSGN / 64, T, 0, stream>>>(v_data, vneg, dbvo);
    dbh_fast<<<NH / 64, T, 0, stream>>>(h1d, h1c, dbh1o);
    dbh_fast<<<NH / 64, T, 0, stream>>>(h2d, h2n, dbh2o);

    zero_kernel<<<1, 1, 0, stream>>>(cnt);
    loss_count2<<<1024, T, 0, stream>>>(v_data, vneg, cnt);
    loss_final_kernel<<<1, 1, 0, stream>>>(cnt, out, logf(1.0f + 1e-7f), logf(1e-7f));
}